// Round 4
// baseline (777.375 us; speedup 1.0000x reference)
//
#include <hip/hip_runtime.h>

#define N_NODES 50000
#define N_EDGES 800000
#define N_GRAPHS 256
#define DIM 128

#define SCAN_B 1024
#define SCAN_NB 49   // ceil(50000/1024)

// ---------------- histogram of dst ----------------
__global__ __launch_bounds__(256) void hist_kernel(const int* __restrict__ dst,
                                                   int* __restrict__ cnt) {
    int e = blockIdx.x * 256 + threadIdx.x;
    if (e < N_EDGES) atomicAdd(&cnt[dst[e]], 1);
}

// ---------------- 3-phase parallel exclusive scan ----------------
__global__ __launch_bounds__(SCAN_B) void reduce_kernel(const int* __restrict__ cnt,
                                                        int* __restrict__ blocksum) {
    __shared__ int red[SCAN_B / 64];
    int idx = blockIdx.x * SCAN_B + threadIdx.x;
    int v = (idx < N_NODES) ? cnt[idx] : 0;
    for (int d = 32; d >= 1; d >>= 1) v += __shfl_down(v, d, 64);
    int wid = threadIdx.x >> 6;
    if ((threadIdx.x & 63) == 0) red[wid] = v;
    __syncthreads();
    if (threadIdx.x == 0) {
        int s = 0;
        for (int w = 0; w < SCAN_B / 64; ++w) s += red[w];
        blocksum[blockIdx.x] = s;
    }
}

__global__ __launch_bounds__(64) void scanblk_kernel(int* __restrict__ blocksum) {
    __shared__ int s[64];
    int t = threadIdx.x;
    s[t] = (t < SCAN_NB) ? blocksum[t] : 0;
    __syncthreads();
    if (t == 0) {
        int run = 0;
        for (int i = 0; i < SCAN_NB; ++i) {
            int c = s[i];
            blocksum[i] = run;
            run += c;
        }
    }
}

__global__ __launch_bounds__(SCAN_B) void scanout_kernel(const int* __restrict__ cnt,
                                                         const int* __restrict__ blockoff,
                                                         int* __restrict__ rowptr,
                                                         int* __restrict__ cursor,
                                                         float* __restrict__ dinv) {
    __shared__ int s[SCAN_B];
    int t = threadIdx.x;
    int idx = blockIdx.x * SCAN_B + t;
    int c = (idx < N_NODES) ? cnt[idx] : 0;
    s[t] = c;
    __syncthreads();
    for (int d = 1; d < SCAN_B; d <<= 1) {
        int v = s[t];
        if (t >= d) v += s[t - d];
        __syncthreads();
        s[t] = v;
        __syncthreads();
    }
    if (idx < N_NODES) {
        int excl = blockoff[blockIdx.x] + s[t] - c;
        rowptr[idx] = excl;
        cursor[idx] = excl;
        dinv[idx] = rsqrtf((float)(c + 1));
        if (idx == 0) rowptr[N_NODES] = N_EDGES;
    }
}

// ---------------- scatter edges into CSR ----------------
__global__ __launch_bounds__(256) void scatter_kernel(const int* __restrict__ src,
                                                      const int* __restrict__ dst,
                                                      int* __restrict__ cursor,
                                                      int* __restrict__ ssrc) {
    int e = blockIdx.x * 256 + threadIdx.x;
    if (e < N_EDGES) {
        int d = dst[e];
        int pos = atomicAdd(&cursor[d], 1);
        ssrc[pos] = src[e];
    }
}

// ---------------- Y[n,128] = X[n,128] @ W[128,128] (fp32) ----------------
__global__ __launch_bounds__(256) void mm128_kernel(const float* __restrict__ X,
                                                    const float* __restrict__ W,
                                                    float* __restrict__ Y, int nrows) {
    __shared__ float Ws[128 * 128];   // 64 KB
    __shared__ float Xs[32 * 128];    // 16 KB
    const float4* W4 = (const float4*)W;
    float4* Ws4 = (float4*)Ws;
    for (int i = threadIdx.x; i < 4096; i += 256) Ws4[i] = W4[i];

    const float4* X4 = (const float4*)X;
    float4* Xs4 = (float4*)Xs;
    float4* Y4 = (float4*)Y;
    int ntiles = (nrows + 31) >> 5;
    for (int tile = blockIdx.x; tile < ntiles; tile += gridDim.x) {
        int r0 = tile << 5;
        __syncthreads();
        for (int i = threadIdx.x; i < 1024; i += 256) {
            int row = i >> 5, q = i & 31;
            int gr = r0 + row;
            Xs4[i] = (gr < nrows) ? X4[gr * 32 + q] : make_float4(0.f, 0.f, 0.f, 0.f);
        }
        __syncthreads();
        int grp = threadIdx.x >> 5;
        int l32 = threadIdx.x & 31;
        float4 a0 = {0, 0, 0, 0}, a1 = a0, a2 = a0, a3 = a0;
#pragma unroll 4
        for (int k = 0; k < 128; ++k) {
            float4 w = Ws4[k * 32 + l32];
            float x0 = Xs[(grp * 4 + 0) * 128 + k];
            float x1 = Xs[(grp * 4 + 1) * 128 + k];
            float x2 = Xs[(grp * 4 + 2) * 128 + k];
            float x3 = Xs[(grp * 4 + 3) * 128 + k];
            a0.x += x0 * w.x; a0.y += x0 * w.y; a0.z += x0 * w.z; a0.w += x0 * w.w;
            a1.x += x1 * w.x; a1.y += x1 * w.y; a1.z += x1 * w.z; a1.w += x1 * w.w;
            a2.x += x2 * w.x; a2.y += x2 * w.y; a2.z += x2 * w.z; a2.w += x2 * w.w;
            a3.x += x3 * w.x; a3.y += x3 * w.y; a3.z += x3 * w.z; a3.w += x3 * w.w;
        }
        int rb = r0 + grp * 4;
        if (rb + 0 < nrows) Y4[(rb + 0) * 32 + l32] = a0;
        if (rb + 1 < nrows) Y4[(rb + 1) * 32 + l32] = a1;
        if (rb + 2 < nrows) Y4[(rb + 2) * 32 + l32] = a2;
        if (rb + 3 < nrows) Y4[(rb + 3) * 32 + l32] = a3;
    }
}

// ---------------- aggregation: XCD-pinned feature slices ----------------
// slice = blockIdx.x & 7 -> under round-robin block->XCD dispatch, each XCD
// only ever touches a 3.2 MB slice of H, which fits its 4 MB L2.
// Persistent grid (2048 blocks, 8/CU) so the binding never erodes.
// Wave layout: lane = (q = lane>>4 edge-quad, f = lane&15 feature).
__global__ __launch_bounds__(256) void agg_kernel(const float* __restrict__ H,
                                                  const int* __restrict__ rowptr,
                                                  const int* __restrict__ ssrc,
                                                  const float* __restrict__ dinv,
                                                  const float* __restrict__ bias,
                                                  float* __restrict__ O) {
    int slice = blockIdx.x & 7;
    int blk_in_slice = blockIdx.x >> 3;            // 0..255
    int gw = blk_in_slice * 4 + (threadIdx.x >> 6); // wave id within slice 0..1023
    int lane = threadIdx.x & 63;
    int f = lane & 15;
    int q = lane >> 4;
    int col = slice * 16 + f;
    float bval = bias[col];
    for (int v = gw; v < N_NODES; v += 1024) {
        float dv = dinv[v];
        int e0 = rowptr[v], eend = rowptr[v + 1];
        float a = 0.f;
        for (int e = e0; e < eend; e += 4) {
            int ee = e + q;
            bool inb = ee < eend;
            int s = ssrc[inb ? ee : e];            // clamp: always a valid edge of this row
            float w = inb ? dinv[s] * dv : 0.f;
            float hval = H[(size_t)s * DIM + col];
            a += w * hval;
        }
        a += __shfl_xor(a, 16, 64);
        a += __shfl_xor(a, 32, 64);
        if (q == 0) {
            float hself = H[(size_t)v * DIM + col];
            float o = fmaxf(a + dv * dv * hself + bval, 0.f);
            O[(size_t)v * DIM + col] = o;
        }
    }
}

// ---------------- mean pool per graph (batch is sorted) ----------------
__device__ __forceinline__ int lbound(const int* __restrict__ a, int n, int v) {
    int lo = 0, hi = n;
    while (lo < hi) {
        int mid = (lo + hi) >> 1;
        if (a[mid] < v) lo = mid + 1; else hi = mid;
    }
    return lo;
}

__global__ __launch_bounds__(512) void pool_kernel(const float* __restrict__ H,
                                                   const int* __restrict__ batch,
                                                   float* __restrict__ P) {
    int g = blockIdx.x;
    __shared__ int sse[2];
    __shared__ float red[512];
    if (threadIdx.x < 2) sse[threadIdx.x] = lbound(batch, N_NODES, g + threadIdx.x);
    __syncthreads();
    int ss = sse[0], se = sse[1];
    int d = threadIdx.x & 127, c = threadIdx.x >> 7;
    float sum = 0.f;
    for (int n = ss + c; n < se; n += 4) sum += H[(size_t)n * 128 + d];
    red[threadIdx.x] = sum;
    __syncthreads();
    if (threadIdx.x < 128) {
        float s = red[threadIdx.x] + red[threadIdx.x + 128] + red[threadIdx.x + 256] + red[threadIdx.x + 384];
        float cntf = (float)(se - ss);
        P[g * 128 + threadIdx.x] = s / fmaxf(cntf, 1.f);
    }
}

// ---------------- MLP + log_softmax ----------------
__global__ __launch_bounds__(128) void mlp_kernel(const float* __restrict__ P1,
                                                  const float* __restrict__ P2,
                                                  const float* __restrict__ L1W,
                                                  const float* __restrict__ L1b,
                                                  const float* __restrict__ L2W,
                                                  const float* __restrict__ L2b,
                                                  float* __restrict__ out) {
    int g = blockIdx.x, j = threadIdx.x;
    __shared__ float gv[256];
    __shared__ float hid[128];
    gv[j] = P1[g * 128 + j];
    gv[128 + j] = P2[g * 128 + j];
    __syncthreads();
    float acc = L1b[j];
#pragma unroll 8
    for (int k = 0; k < 256; ++k) acc = fmaf(gv[k], L1W[k * 128 + j], acc);
    hid[j] = fmaxf(acc, 0.f);
    __syncthreads();
    if (j == 0) {
        float o0 = L2b[0], o1 = L2b[1];
        for (int k = 0; k < 128; ++k) {
            o0 += hid[k] * L2W[2 * k + 0];
            o1 += hid[k] * L2W[2 * k + 1];
        }
        float m = fmaxf(o0, o1);
        float lse = m + logf(expf(o0 - m) + expf(o1 - m));
        out[g * 2 + 0] = o0 - lse;
        out[g * 2 + 1] = o1 - lse;
    }
}

extern "C" void kernel_launch(void* const* d_in, const int* in_sizes, int n_in,
                              void* d_out, int out_size, void* d_ws, size_t ws_size,
                              hipStream_t stream) {
    const float* x    = (const float*)d_in[0];
    const int*   ei   = (const int*)d_in[1];    // [2, N_EDGES]: src row then dst row
    const int*   batch= (const int*)d_in[2];
    const float* W1   = (const float*)d_in[3];
    const float* b1   = (const float*)d_in[4];
    const float* W2   = (const float*)d_in[5];
    const float* b2   = (const float*)d_in[6];
    const float* L1W  = (const float*)d_in[7];
    const float* L1b  = (const float*)d_in[8];
    const float* L2W  = (const float*)d_in[9];
    const float* L2b  = (const float*)d_in[10];
    float* out = (float*)d_out;

    const int* e_src = ei;
    const int* e_dst = ei + N_EDGES;

    char* ws = (char*)d_ws;
    size_t off = 0;
    auto alloc = [&](size_t bytes) {
        void* p = ws + off;
        off += (bytes + 255) & ~(size_t)255;
        return p;
    };
    int*   deg_cnt   = (int*)alloc(N_NODES * 4);
    int*   rowptr    = (int*)alloc((N_NODES + 1) * 4);
    int*   cursor    = (int*)alloc(N_NODES * 4);
    int*   ssrc      = (int*)alloc(N_EDGES * 4);
    float* dinv      = (float*)alloc(N_NODES * 4);
    int*   blocksum  = (int*)alloc(SCAN_NB * 4);
    float* p1        = (float*)alloc(N_GRAPHS * DIM * 4);
    float* p2        = (float*)alloc(N_GRAPHS * DIM * 4);
    float* bufA      = (float*)alloc((size_t)N_NODES * DIM * 4);
    float* bufB      = (float*)alloc((size_t)N_NODES * DIM * 4);
    (void)ws_size; (void)in_sizes; (void)n_in; (void)out_size;

    hipMemsetAsync(deg_cnt, 0, N_NODES * 4, stream);

    const int EB = (N_EDGES + 255) / 256;      // 3125
    hist_kernel<<<EB, 256, 0, stream>>>(e_dst, deg_cnt);
    reduce_kernel<<<SCAN_NB, SCAN_B, 0, stream>>>(deg_cnt, blocksum);
    scanblk_kernel<<<1, 64, 0, stream>>>(blocksum);
    scanout_kernel<<<SCAN_NB, SCAN_B, 0, stream>>>(deg_cnt, blocksum, rowptr, cursor, dinv);
    scatter_kernel<<<EB, 256, 0, stream>>>(e_src, e_dst, cursor, ssrc);

    const int MMB = (N_NODES + 31) / 32;       // 1563
    const int AGB = 2048;                      // persistent-style: 8 blocks/CU

    // conv1
    mm128_kernel<<<MMB, 256, 0, stream>>>(x, W1, bufA, N_NODES);
    agg_kernel<<<AGB, 256, 0, stream>>>(bufA, rowptr, ssrc, dinv, b1, bufB);  // h1
    pool_kernel<<<N_GRAPHS, 512, 0, stream>>>(bufB, batch, p1);

    // conv2
    mm128_kernel<<<MMB, 256, 0, stream>>>(bufB, W2, bufA, N_NODES);
    agg_kernel<<<AGB, 256, 0, stream>>>(bufA, rowptr, ssrc, dinv, b2, bufB);  // h2 overwrites h1
    pool_kernel<<<N_GRAPHS, 512, 0, stream>>>(bufB, batch, p2);

    // head
    mlp_kernel<<<N_GRAPHS, 128, 0, stream>>>(p1, p2, L1W, L1b, L2W, L2b, out);
}

// Round 6
// 445.010 us; speedup vs baseline: 1.7469x; 1.7469x over previous
//
#include <hip/hip_runtime.h>

#define N_NODES 50000
#define N_EDGES 800000
#define N_GRAPHS 256
#define DIM 128

#define SCAN_B 1024
#define SCAN_NB 49   // ceil(50000/1024)

__device__ __forceinline__ unsigned short f2bf(float f) {
    union { float f; unsigned u; } v; v.f = f;
    unsigned u = v.u;
    u += 0x7fffu + ((u >> 16) & 1u);   // round-to-nearest-even
    return (unsigned short)(u >> 16);
}
__device__ __forceinline__ float bf2f(unsigned short h) {
    union { unsigned u; float f; } v; v.u = ((unsigned)h) << 16;
    return v.f;
}

// ---------------- histogram of dst ----------------
__global__ __launch_bounds__(256) void hist_kernel(const int* __restrict__ dst,
                                                   int* __restrict__ cnt) {
    int e = blockIdx.x * 256 + threadIdx.x;
    if (e < N_EDGES) atomicAdd(&cnt[dst[e]], 1);
}

// ---------------- 3-phase parallel exclusive scan ----------------
__global__ __launch_bounds__(SCAN_B) void reduce_kernel(const int* __restrict__ cnt,
                                                        int* __restrict__ blocksum) {
    __shared__ int red[SCAN_B / 64];
    int idx = blockIdx.x * SCAN_B + threadIdx.x;
    int v = (idx < N_NODES) ? cnt[idx] : 0;
    for (int d = 32; d >= 1; d >>= 1) v += __shfl_down(v, d, 64);
    int wid = threadIdx.x >> 6;
    if ((threadIdx.x & 63) == 0) red[wid] = v;
    __syncthreads();
    if (threadIdx.x == 0) {
        int s = 0;
        for (int w = 0; w < SCAN_B / 64; ++w) s += red[w];
        blocksum[blockIdx.x] = s;
    }
}

__global__ __launch_bounds__(64) void scanblk_kernel(int* __restrict__ blocksum) {
    __shared__ int s[64];
    int t = threadIdx.x;
    s[t] = (t < SCAN_NB) ? blocksum[t] : 0;
    __syncthreads();
    if (t == 0) {
        int run = 0;
        for (int i = 0; i < SCAN_NB; ++i) {
            int c = s[i];
            blocksum[i] = run;
            run += c;
        }
    }
}

__global__ __launch_bounds__(SCAN_B) void scanout_kernel(const int* __restrict__ cnt,
                                                         const int* __restrict__ blockoff,
                                                         int* __restrict__ rowptr,
                                                         int* __restrict__ cursor,
                                                         float* __restrict__ dinv) {
    __shared__ int s[SCAN_B];
    int t = threadIdx.x;
    int idx = blockIdx.x * SCAN_B + t;
    int c = (idx < N_NODES) ? cnt[idx] : 0;
    s[t] = c;
    __syncthreads();
    for (int d = 1; d < SCAN_B; d <<= 1) {
        int v = s[t];
        if (t >= d) v += s[t - d];
        __syncthreads();
        s[t] = v;
        __syncthreads();
    }
    if (idx < N_NODES) {
        int excl = blockoff[blockIdx.x] + s[t] - c;
        rowptr[idx] = excl;
        cursor[idx] = excl;
        dinv[idx] = rsqrtf((float)(c + 1));
        if (idx == 0) rowptr[N_NODES] = N_EDGES;
    }
}

// ---------------- scatter edges into CSR ----------------
__global__ __launch_bounds__(256) void scatter_kernel(const int* __restrict__ src,
                                                      const int* __restrict__ dst,
                                                      int* __restrict__ cursor,
                                                      int* __restrict__ ssrc) {
    int e = blockIdx.x * 256 + threadIdx.x;
    if (e < N_EDGES) {
        int d = dst[e];
        int pos = atomicAdd(&cursor[d], 1);
        ssrc[pos] = src[e];
    }
}

// ---------------- Ybf[n,128](bf16) = X[n,128] @ W[128,128] (fp32 math) ----------------
__global__ __launch_bounds__(256) void mm128_kernel(const float* __restrict__ X,
                                                    const float* __restrict__ W,
                                                    unsigned short* __restrict__ Y, int nrows) {
    __shared__ float Ws[128 * 128];   // 64 KB
    __shared__ float Xs[32 * 128];    // 16 KB
    const float4* W4 = (const float4*)W;
    float4* Ws4 = (float4*)Ws;
    for (int i = threadIdx.x; i < 4096; i += 256) Ws4[i] = W4[i];

    const float4* X4 = (const float4*)X;
    float4* Xs4 = (float4*)Xs;
    ushort4* Y4 = (ushort4*)Y;
    int ntiles = (nrows + 31) >> 5;
    for (int tile = blockIdx.x; tile < ntiles; tile += gridDim.x) {
        int r0 = tile << 5;
        __syncthreads();
        for (int i = threadIdx.x; i < 1024; i += 256) {
            int row = i >> 5, q = i & 31;
            int gr = r0 + row;
            Xs4[i] = (gr < nrows) ? X4[gr * 32 + q] : make_float4(0.f, 0.f, 0.f, 0.f);
        }
        __syncthreads();
        int grp = threadIdx.x >> 5;
        int l32 = threadIdx.x & 31;
        float4 a0 = {0, 0, 0, 0}, a1 = a0, a2 = a0, a3 = a0;
#pragma unroll 4
        for (int k = 0; k < 128; ++k) {
            float4 w = Ws4[k * 32 + l32];
            float x0 = Xs[(grp * 4 + 0) * 128 + k];
            float x1 = Xs[(grp * 4 + 1) * 128 + k];
            float x2 = Xs[(grp * 4 + 2) * 128 + k];
            float x3 = Xs[(grp * 4 + 3) * 128 + k];
            a0.x += x0 * w.x; a0.y += x0 * w.y; a0.z += x0 * w.z; a0.w += x0 * w.w;
            a1.x += x1 * w.x; a1.y += x1 * w.y; a1.z += x1 * w.z; a1.w += x1 * w.w;
            a2.x += x2 * w.x; a2.y += x2 * w.y; a2.z += x2 * w.z; a2.w += x2 * w.w;
            a3.x += x3 * w.x; a3.y += x3 * w.y; a3.z += x3 * w.z; a3.w += x3 * w.w;
        }
        int rb = r0 + grp * 4;
        ushort4 c0 = {f2bf(a0.x), f2bf(a0.y), f2bf(a0.z), f2bf(a0.w)};
        ushort4 c1 = {f2bf(a1.x), f2bf(a1.y), f2bf(a1.z), f2bf(a1.w)};
        ushort4 c2 = {f2bf(a2.x), f2bf(a2.y), f2bf(a2.z), f2bf(a2.w)};
        ushort4 c3 = {f2bf(a3.x), f2bf(a3.y), f2bf(a3.z), f2bf(a3.w)};
        if (rb + 0 < nrows) Y4[(rb + 0) * 32 + l32] = c0;
        if (rb + 1 < nrows) Y4[(rb + 1) * 32 + l32] = c1;
        if (rb + 2 < nrows) Y4[(rb + 2) * 32 + l32] = c2;
        if (rb + 3 < nrows) Y4[(rb + 3) * 32 + l32] = c3;
    }
}

// ---------------- aggregation: one wave per node, bf16 gather ----------------
// Row = 128 bf16 = 256 B = 32 lanes x ushort4. Half-waves service 2 edges
// concurrently; inner loop unrolled to 8 edges in flight.
__global__ __launch_bounds__(256) void agg_kernel(const unsigned short* __restrict__ Hbf,
                                                  const int* __restrict__ rowptr,
                                                  const int* __restrict__ ssrc,
                                                  const float* __restrict__ dinv,
                                                  const float* __restrict__ bias,
                                                  float* __restrict__ O) {
    int gw = (int)((blockIdx.x * 256 + threadIdx.x) >> 6);
    if (gw >= N_NODES) return;
    int v = __builtin_amdgcn_readfirstlane(gw);
    int lane = threadIdx.x & 63;
    int half = lane >> 5;
    int l = lane & 31;
    const ushort4* H4 = (const ushort4*)Hbf;   // row stride 32
    float dv = dinv[v];
    float ax = 0.f, ay = 0.f, az = 0.f, aw = 0.f;
    int e0 = rowptr[v], eend = rowptr[v + 1];
    for (int base = e0; base < eend; base += 8) {
#pragma unroll
        for (int k = 0; k < 4; ++k) {
            int ee = base + 2 * k + half;
            bool inb = ee < eend;
            int s = ssrc[inb ? ee : e0];
            float w = inb ? dinv[s] * dv : 0.f;
            ushort4 h = H4[(size_t)s * 32 + l];
            ax += w * bf2f(h.x);
            ay += w * bf2f(h.y);
            az += w * bf2f(h.z);
            aw += w * bf2f(h.w);
        }
    }
    ax += __shfl_xor(ax, 32, 64);
    ay += __shfl_xor(ay, 32, 64);
    az += __shfl_xor(az, 32, 64);
    aw += __shfl_xor(aw, 32, 64);
    if (half == 0) {
        ushort4 hs = H4[(size_t)v * 32 + l];
        float sc = dv * dv;
        float4 b4 = ((const float4*)bias)[l];
        float4 o;
        o.x = fmaxf(ax + sc * bf2f(hs.x) + b4.x, 0.f);
        o.y = fmaxf(ay + sc * bf2f(hs.y) + b4.y, 0.f);
        o.z = fmaxf(az + sc * bf2f(hs.z) + b4.z, 0.f);
        o.w = fmaxf(aw + sc * bf2f(hs.w) + b4.w, 0.f);
        ((float4*)O)[(size_t)v * 32 + l] = o;
    }
}

// ---------------- mean pool per graph (batch is sorted) ----------------
__device__ __forceinline__ int lbound(const int* __restrict__ a, int n, int v) {
    int lo = 0, hi = n;
    while (lo < hi) {
        int mid = (lo + hi) >> 1;
        if (a[mid] < v) lo = mid + 1; else hi = mid;
    }
    return lo;
}

__global__ __launch_bounds__(512) void pool_kernel(const float* __restrict__ H,
                                                   const int* __restrict__ batch,
                                                   float* __restrict__ P) {
    int g = blockIdx.x;
    __shared__ int sse[2];
    __shared__ float red[512];
    if (threadIdx.x < 2) sse[threadIdx.x] = lbound(batch, N_NODES, g + threadIdx.x);
    __syncthreads();
    int ss = sse[0], se = sse[1];
    int d = threadIdx.x & 127, c = threadIdx.x >> 7;
    float sum = 0.f;
    for (int n = ss + c; n < se; n += 4) sum += H[(size_t)n * 128 + d];
    red[threadIdx.x] = sum;
    __syncthreads();
    if (threadIdx.x < 128) {
        float s = red[threadIdx.x] + red[threadIdx.x + 128] + red[threadIdx.x + 256] + red[threadIdx.x + 384];
        float cntf = (float)(se - ss);
        P[g * 128 + threadIdx.x] = s / fmaxf(cntf, 1.f);
    }
}

// ---------------- MLP + log_softmax ----------------
__global__ __launch_bounds__(128) void mlp_kernel(const float* __restrict__ P1,
                                                  const float* __restrict__ P2,
                                                  const float* __restrict__ L1W,
                                                  const float* __restrict__ L1b,
                                                  const float* __restrict__ L2W,
                                                  const float* __restrict__ L2b,
                                                  float* __restrict__ out) {
    int g = blockIdx.x, j = threadIdx.x;
    __shared__ float gv[256];
    __shared__ float hid[128];
    gv[j] = P1[g * 128 + j];
    gv[128 + j] = P2[g * 128 + j];
    __syncthreads();
    float acc = L1b[j];
#pragma unroll 8
    for (int k = 0; k < 256; ++k) acc = fmaf(gv[k], L1W[k * 128 + j], acc);
    hid[j] = fmaxf(acc, 0.f);
    __syncthreads();
    if (j == 0) {
        float o0 = L2b[0], o1 = L2b[1];
        for (int k = 0; k < 128; ++k) {
            o0 += hid[k] * L2W[2 * k + 0];
            o1 += hid[k] * L2W[2 * k + 1];
        }
        float m = fmaxf(o0, o1);
        float lse = m + logf(expf(o0 - m) + expf(o1 - m));
        out[g * 2 + 0] = o0 - lse;
        out[g * 2 + 1] = o1 - lse;
    }
}

extern "C" void kernel_launch(void* const* d_in, const int* in_sizes, int n_in,
                              void* d_out, int out_size, void* d_ws, size_t ws_size,
                              hipStream_t stream) {
    const float* x    = (const float*)d_in[0];
    const int*   ei   = (const int*)d_in[1];    // [2, N_EDGES]: src row then dst row
    const int*   batch= (const int*)d_in[2];
    const float* W1   = (const float*)d_in[3];
    const float* b1   = (const float*)d_in[4];
    const float* W2   = (const float*)d_in[5];
    const float* b2   = (const float*)d_in[6];
    const float* L1W  = (const float*)d_in[7];
    const float* L1b  = (const float*)d_in[8];
    const float* L2W  = (const float*)d_in[9];
    const float* L2b  = (const float*)d_in[10];
    float* out = (float*)d_out;

    const int* e_src = ei;
    const int* e_dst = ei + N_EDGES;

    char* ws = (char*)d_ws;
    size_t off = 0;
    auto alloc = [&](size_t bytes) {
        void* p = ws + off;
        off += (bytes + 255) & ~(size_t)255;
        return p;
    };
    int*   deg_cnt   = (int*)alloc(N_NODES * 4);
    int*   rowptr    = (int*)alloc((N_NODES + 1) * 4);
    int*   cursor    = (int*)alloc(N_NODES * 4);
    int*   ssrc      = (int*)alloc(N_EDGES * 4);
    float* dinv      = (float*)alloc(N_NODES * 4);
    int*   blocksum  = (int*)alloc(SCAN_NB * 4);
    float* p1        = (float*)alloc(N_GRAPHS * DIM * 4);
    float* p2        = (float*)alloc(N_GRAPHS * DIM * 4);
    unsigned short* bufBf = (unsigned short*)alloc((size_t)N_NODES * DIM * 2);
    float* bufB      = (float*)alloc((size_t)N_NODES * DIM * 4);
    (void)ws_size; (void)in_sizes; (void)n_in; (void)out_size;

    hipMemsetAsync(deg_cnt, 0, N_NODES * 4, stream);

    const int EB = (N_EDGES + 255) / 256;      // 3125
    hist_kernel<<<EB, 256, 0, stream>>>(e_dst, deg_cnt);
    reduce_kernel<<<SCAN_NB, SCAN_B, 0, stream>>>(deg_cnt, blocksum);
    scanblk_kernel<<<1, 64, 0, stream>>>(blocksum);
    scanout_kernel<<<SCAN_NB, SCAN_B, 0, stream>>>(deg_cnt, blocksum, rowptr, cursor, dinv);
    scatter_kernel<<<EB, 256, 0, stream>>>(e_src, e_dst, cursor, ssrc);

    const int MMB = (N_NODES + 31) / 32;        // 1563
    const int AGB = (N_NODES * 64 + 255) / 256; // 12500

    // conv1
    mm128_kernel<<<MMB, 256, 0, stream>>>(x, W1, bufBf, N_NODES);
    agg_kernel<<<AGB, 256, 0, stream>>>(bufBf, rowptr, ssrc, dinv, b1, bufB);  // h1 (fp32)
    pool_kernel<<<N_GRAPHS, 512, 0, stream>>>(bufB, batch, p1);

    // conv2
    mm128_kernel<<<MMB, 256, 0, stream>>>(bufB, W2, bufBf, N_NODES);
    agg_kernel<<<AGB, 256, 0, stream>>>(bufBf, rowptr, ssrc, dinv, b2, bufB);  // h2 overwrites h1
    pool_kernel<<<N_GRAPHS, 512, 0, stream>>>(bufB, batch, p2);

    // head
    mlp_kernel<<<N_GRAPHS, 128, 0, stream>>>(p1, p2, L1W, L1b, L2W, L2b, out);
}

// Round 7
// 373.000 us; speedup vs baseline: 2.0841x; 1.1931x over previous
//
#include <hip/hip_runtime.h>

#define N_NODES 50000
#define N_EDGES 800000
#define N_GRAPHS 256
#define DIM 128

#define SCAN_B 1024
#define SCAN_NB 49   // ceil(50000/1024)

typedef __attribute__((ext_vector_type(8))) short bf16x8;
typedef __attribute__((ext_vector_type(4))) float f32x4;

__device__ __forceinline__ unsigned short f2bf(float f) {
    union { float f; unsigned u; } v; v.f = f;
    unsigned u = v.u;
    u += 0x7fffu + ((u >> 16) & 1u);   // round-to-nearest-even
    return (unsigned short)(u >> 16);
}
__device__ __forceinline__ float bf2f(unsigned short h) {
    union { unsigned u; float f; } v; v.u = ((unsigned)h) << 16;
    return v.f;
}

// ---------------- histogram of dst ----------------
__global__ __launch_bounds__(256) void hist_kernel(const int* __restrict__ dst,
                                                   int* __restrict__ cnt) {
    int e = blockIdx.x * 256 + threadIdx.x;
    if (e < N_EDGES) atomicAdd(&cnt[dst[e]], 1);
}

// ---------------- 3-phase parallel exclusive scan ----------------
__global__ __launch_bounds__(SCAN_B) void reduce_kernel(const int* __restrict__ cnt,
                                                        int* __restrict__ blocksum) {
    __shared__ int red[SCAN_B / 64];
    int idx = blockIdx.x * SCAN_B + threadIdx.x;
    int v = (idx < N_NODES) ? cnt[idx] : 0;
    for (int d = 32; d >= 1; d >>= 1) v += __shfl_down(v, d, 64);
    int wid = threadIdx.x >> 6;
    if ((threadIdx.x & 63) == 0) red[wid] = v;
    __syncthreads();
    if (threadIdx.x == 0) {
        int s = 0;
        for (int w = 0; w < SCAN_B / 64; ++w) s += red[w];
        blocksum[blockIdx.x] = s;
    }
}

__global__ __launch_bounds__(64) void scanblk_kernel(int* __restrict__ blocksum) {
    __shared__ int s[64];
    int t = threadIdx.x;
    s[t] = (t < SCAN_NB) ? blocksum[t] : 0;
    __syncthreads();
    if (t == 0) {
        int run = 0;
        for (int i = 0; i < SCAN_NB; ++i) {
            int c = s[i];
            blocksum[i] = run;
            run += c;
        }
    }
}

__global__ __launch_bounds__(SCAN_B) void scanout_kernel(const int* __restrict__ cnt,
                                                         const int* __restrict__ blockoff,
                                                         int* __restrict__ rowptr,
                                                         int* __restrict__ cursor,
                                                         float* __restrict__ dinv) {
    __shared__ int s[SCAN_B];
    int t = threadIdx.x;
    int idx = blockIdx.x * SCAN_B + t;
    int c = (idx < N_NODES) ? cnt[idx] : 0;
    s[t] = c;
    __syncthreads();
    for (int d = 1; d < SCAN_B; d <<= 1) {
        int v = s[t];
        if (t >= d) v += s[t - d];
        __syncthreads();
        s[t] = v;
        __syncthreads();
    }
    if (idx < N_NODES) {
        int excl = blockoff[blockIdx.x] + s[t] - c;
        rowptr[idx] = excl;
        cursor[idx] = excl;
        dinv[idx] = rsqrtf((float)(c + 1));
        if (idx == 0) rowptr[N_NODES] = N_EDGES;
    }
}

// ---------------- scatter edges into CSR ----------------
__global__ __launch_bounds__(256) void scatter_kernel(const int* __restrict__ src,
                                                      const int* __restrict__ dst,
                                                      int* __restrict__ cursor,
                                                      int* __restrict__ ssrc) {
    int e = blockIdx.x * 256 + threadIdx.x;
    if (e < N_EDGES) {
        int d = dst[e];
        int pos = atomicAdd(&cursor[d], 1);
        ssrc[pos] = src[e];
    }
}

// ---------------- Ybf[n,128](bf16) = X[n,128] @ W[128,128] via MFMA ----------------
// 391 blocks x 256 thr; 128-row tile, full 128 cols. W transposed+bf16 in LDS.
// Fragment layout (verified mapping, cdna4 guide §3):
//   A: lane holds X[r0 + (l&15)][ks*32 + (l>>4)*8 + j], j=0..7 contiguous
//   B: lane holds W[ks*32 + (l>>4)*8 + j][c0 + (l&15)]  (read from Wt rows)
//   C/D: row = (l>>4)*4 + reg, col = l&15
#define LDK 136   // padded LDS row stride in shorts (272 B: 16B-aligned, bank-friendly)
__global__ __launch_bounds__(256) void mm_mfma_kernel(const float* __restrict__ X,
                                                      const float* __restrict__ W,
                                                      unsigned short* __restrict__ Y,
                                                      int nrows) {
    __shared__ __align__(16) unsigned short Xs[128 * LDK];   // 34.8 KB
    __shared__ __align__(16) unsigned short Wt[128 * LDK];   // 34.8 KB
    int t = threadIdx.x;

    // stage W transposed: Wt[c][k] = bf16(W[k][c])
    for (int idx = t; idx < 128 * 128; idx += 256) {
        int k = idx >> 7, c = idx & 127;
        Wt[c * LDK + k] = f2bf(W[idx]);
    }
    // stage X tile rows [r0, r0+128) as bf16
    int r0 = blockIdx.x * 128;
    const float4* X4 = (const float4*)X;
    for (int idx = t; idx < 128 * 32; idx += 256) {
        int r = idx >> 5, q = idx & 31;
        int gr = r0 + r;
        float4 vv = (gr < nrows) ? X4[(size_t)gr * 32 + q] : make_float4(0.f, 0.f, 0.f, 0.f);
        int base = r * LDK + q * 4;
        Xs[base + 0] = f2bf(vv.x);
        Xs[base + 1] = f2bf(vv.y);
        Xs[base + 2] = f2bf(vv.z);
        Xs[base + 3] = f2bf(vv.w);
    }
    __syncthreads();

    int w  = t >> 6;       // wave 0..3 -> rows w*32 .. w*32+31
    int l  = t & 63;
    int lg = l >> 4;       // lane-group = k-chunk
    int lr = l & 15;

    f32x4 acc[2][8];
#pragma unroll
    for (int rs = 0; rs < 2; ++rs)
#pragma unroll
        for (int cs = 0; cs < 8; ++cs) acc[rs][cs] = (f32x4){0.f, 0.f, 0.f, 0.f};

#pragma unroll
    for (int ks = 0; ks < 4; ++ks) {
        int koff = ks * 32 + lg * 8;
        bf16x8 a0 = *(const bf16x8*)&Xs[(w * 32 + 0 + lr) * LDK + koff];
        bf16x8 a1 = *(const bf16x8*)&Xs[(w * 32 + 16 + lr) * LDK + koff];
#pragma unroll
        for (int cs = 0; cs < 8; ++cs) {
            bf16x8 b = *(const bf16x8*)&Wt[(cs * 16 + lr) * LDK + koff];
            acc[0][cs] = __builtin_amdgcn_mfma_f32_16x16x32_bf16(a0, b, acc[0][cs], 0, 0, 0);
            acc[1][cs] = __builtin_amdgcn_mfma_f32_16x16x32_bf16(a1, b, acc[1][cs], 0, 0, 0);
        }
    }

    // write out bf16
#pragma unroll
    for (int rs = 0; rs < 2; ++rs) {
        int rbase = r0 + w * 32 + rs * 16 + lg * 4;
#pragma unroll
        for (int cs = 0; cs < 8; ++cs) {
            int c = cs * 16 + lr;
#pragma unroll
            for (int reg = 0; reg < 4; ++reg) {
                int r = rbase + reg;
                if (r < nrows) Y[(size_t)r * 128 + c] = f2bf(acc[rs][cs][reg]);
            }
        }
    }
}

// ---------------- aggregation: one wave per node, bf16 gather ----------------
__global__ __launch_bounds__(256) void agg_kernel(const unsigned short* __restrict__ Hbf,
                                                  const int* __restrict__ rowptr,
                                                  const int* __restrict__ ssrc,
                                                  const float* __restrict__ dinv,
                                                  const float* __restrict__ bias,
                                                  float* __restrict__ O) {
    int gw = (int)((blockIdx.x * 256 + threadIdx.x) >> 6);
    if (gw >= N_NODES) return;
    int v = __builtin_amdgcn_readfirstlane(gw);
    int lane = threadIdx.x & 63;
    int half = lane >> 5;
    int l = lane & 31;
    const ushort4* H4 = (const ushort4*)Hbf;   // row stride 32
    float dv = dinv[v];
    float ax = 0.f, ay = 0.f, az = 0.f, aw = 0.f;
    int e0 = rowptr[v], eend = rowptr[v + 1];
    for (int base = e0; base < eend; base += 8) {
#pragma unroll
        for (int k = 0; k < 4; ++k) {
            int ee = base + 2 * k + half;
            bool inb = ee < eend;
            int s = ssrc[inb ? ee : e0];
            float w = inb ? dinv[s] * dv : 0.f;
            ushort4 h = H4[(size_t)s * 32 + l];
            ax += w * bf2f(h.x);
            ay += w * bf2f(h.y);
            az += w * bf2f(h.z);
            aw += w * bf2f(h.w);
        }
    }
    ax += __shfl_xor(ax, 32, 64);
    ay += __shfl_xor(ay, 32, 64);
    az += __shfl_xor(az, 32, 64);
    aw += __shfl_xor(aw, 32, 64);
    if (half == 0) {
        ushort4 hs = H4[(size_t)v * 32 + l];
        float sc = dv * dv;
        float4 b4 = ((const float4*)bias)[l];
        float4 o;
        o.x = fmaxf(ax + sc * bf2f(hs.x) + b4.x, 0.f);
        o.y = fmaxf(ay + sc * bf2f(hs.y) + b4.y, 0.f);
        o.z = fmaxf(az + sc * bf2f(hs.z) + b4.z, 0.f);
        o.w = fmaxf(aw + sc * bf2f(hs.w) + b4.w, 0.f);
        ((float4*)O)[(size_t)v * 32 + l] = o;
    }
}

// ---------------- mean pool per graph (batch is sorted) ----------------
__device__ __forceinline__ int lbound(const int* __restrict__ a, int n, int v) {
    int lo = 0, hi = n;
    while (lo < hi) {
        int mid = (lo + hi) >> 1;
        if (a[mid] < v) lo = mid + 1; else hi = mid;
    }
    return lo;
}

__global__ __launch_bounds__(512) void pool_kernel(const float* __restrict__ H,
                                                   const int* __restrict__ batch,
                                                   float* __restrict__ P) {
    int g = blockIdx.x;
    __shared__ int sse[2];
    __shared__ float red[512];
    if (threadIdx.x < 2) sse[threadIdx.x] = lbound(batch, N_NODES, g + threadIdx.x);
    __syncthreads();
    int ss = sse[0], se = sse[1];
    int d = threadIdx.x & 127, c = threadIdx.x >> 7;
    float sum = 0.f;
    for (int n = ss + c; n < se; n += 4) sum += H[(size_t)n * 128 + d];
    red[threadIdx.x] = sum;
    __syncthreads();
    if (threadIdx.x < 128) {
        float s = red[threadIdx.x] + red[threadIdx.x + 128] + red[threadIdx.x + 256] + red[threadIdx.x + 384];
        float cntf = (float)(se - ss);
        P[g * 128 + threadIdx.x] = s / fmaxf(cntf, 1.f);
    }
}

// ---------------- MLP + log_softmax ----------------
__global__ __launch_bounds__(128) void mlp_kernel(const float* __restrict__ P1,
                                                  const float* __restrict__ P2,
                                                  const float* __restrict__ L1W,
                                                  const float* __restrict__ L1b,
                                                  const float* __restrict__ L2W,
                                                  const float* __restrict__ L2b,
                                                  float* __restrict__ out) {
    int g = blockIdx.x, j = threadIdx.x;
    __shared__ float gv[256];
    __shared__ float hid[128];
    gv[j] = P1[g * 128 + j];
    gv[128 + j] = P2[g * 128 + j];
    __syncthreads();
    float acc = L1b[j];
#pragma unroll 8
    for (int k = 0; k < 256; ++k) acc = fmaf(gv[k], L1W[k * 128 + j], acc);
    hid[j] = fmaxf(acc, 0.f);
    __syncthreads();
    if (j == 0) {
        float o0 = L2b[0], o1 = L2b[1];
        for (int k = 0; k < 128; ++k) {
            o0 += hid[k] * L2W[2 * k + 0];
            o1 += hid[k] * L2W[2 * k + 1];
        }
        float m = fmaxf(o0, o1);
        float lse = m + logf(expf(o0 - m) + expf(o1 - m));
        out[g * 2 + 0] = o0 - lse;
        out[g * 2 + 1] = o1 - lse;
    }
}

extern "C" void kernel_launch(void* const* d_in, const int* in_sizes, int n_in,
                              void* d_out, int out_size, void* d_ws, size_t ws_size,
                              hipStream_t stream) {
    const float* x    = (const float*)d_in[0];
    const int*   ei   = (const int*)d_in[1];    // [2, N_EDGES]: src row then dst row
    const int*   batch= (const int*)d_in[2];
    const float* W1   = (const float*)d_in[3];
    const float* b1   = (const float*)d_in[4];
    const float* W2   = (const float*)d_in[5];
    const float* b2   = (const float*)d_in[6];
    const float* L1W  = (const float*)d_in[7];
    const float* L1b  = (const float*)d_in[8];
    const float* L2W  = (const float*)d_in[9];
    const float* L2b  = (const float*)d_in[10];
    float* out = (float*)d_out;

    const int* e_src = ei;
    const int* e_dst = ei + N_EDGES;

    char* ws = (char*)d_ws;
    size_t off = 0;
    auto alloc = [&](size_t bytes) {
        void* p = ws + off;
        off += (bytes + 255) & ~(size_t)255;
        return p;
    };
    int*   deg_cnt   = (int*)alloc(N_NODES * 4);
    int*   rowptr    = (int*)alloc((N_NODES + 1) * 4);
    int*   cursor    = (int*)alloc(N_NODES * 4);
    int*   ssrc      = (int*)alloc(N_EDGES * 4);
    float* dinv      = (float*)alloc(N_NODES * 4);
    int*   blocksum  = (int*)alloc(SCAN_NB * 4);
    float* p1        = (float*)alloc(N_GRAPHS * DIM * 4);
    float* p2        = (float*)alloc(N_GRAPHS * DIM * 4);
    unsigned short* bufBf = (unsigned short*)alloc((size_t)N_NODES * DIM * 2);
    float* bufB      = (float*)alloc((size_t)N_NODES * DIM * 4);
    (void)ws_size; (void)in_sizes; (void)n_in; (void)out_size;

    hipMemsetAsync(deg_cnt, 0, N_NODES * 4, stream);

    const int EB = (N_EDGES + 255) / 256;      // 3125
    hist_kernel<<<EB, 256, 0, stream>>>(e_dst, deg_cnt);
    reduce_kernel<<<SCAN_NB, SCAN_B, 0, stream>>>(deg_cnt, blocksum);
    scanblk_kernel<<<1, 64, 0, stream>>>(blocksum);
    scanout_kernel<<<SCAN_NB, SCAN_B, 0, stream>>>(deg_cnt, blocksum, rowptr, cursor, dinv);
    scatter_kernel<<<EB, 256, 0, stream>>>(e_src, e_dst, cursor, ssrc);

    const int MMB = (N_NODES + 127) / 128;      // 391
    const int AGB = (N_NODES * 64 + 255) / 256; // 12500

    // conv1
    mm_mfma_kernel<<<MMB, 256, 0, stream>>>(x, W1, bufBf, N_NODES);
    agg_kernel<<<AGB, 256, 0, stream>>>(bufBf, rowptr, ssrc, dinv, b1, bufB);  // h1 (fp32)
    pool_kernel<<<N_GRAPHS, 512, 0, stream>>>(bufB, batch, p1);

    // conv2
    mm_mfma_kernel<<<MMB, 256, 0, stream>>>(bufB, W2, bufBf, N_NODES);
    agg_kernel<<<AGB, 256, 0, stream>>>(bufBf, rowptr, ssrc, dinv, b2, bufB);  // h2 overwrites h1
    pool_kernel<<<N_GRAPHS, 512, 0, stream>>>(bufB, batch, p2);

    // head
    mlp_kernel<<<N_GRAPHS, 128, 0, stream>>>(p1, p2, L1W, L1b, L2W, L2b, out);
}

// Round 9
// 333.753 us; speedup vs baseline: 2.3292x; 1.1176x over previous
//
#include <hip/hip_runtime.h>

#define N_NODES 50000
#define N_EDGES 800000
#define N_GRAPHS 256
#define DIM 128

#define SCAN_B 1024
#define SCAN_NB 49   // ceil(50000/1024)

typedef __attribute__((ext_vector_type(8))) short bf16x8;
typedef __attribute__((ext_vector_type(4))) float f32x4;
typedef __attribute__((ext_vector_type(8))) unsigned short u16x8;

__device__ __forceinline__ unsigned short f2bf(float f) {
    union { float f; unsigned u; } v; v.f = f;
    unsigned u = v.u;
    u += 0x7fffu + ((u >> 16) & 1u);   // round-to-nearest-even
    return (unsigned short)(u >> 16);
}
__device__ __forceinline__ float bf2f(unsigned short h) {
    union { unsigned u; float f; } v; v.u = ((unsigned)h) << 16;
    return v.f;
}

// ---------------- histogram of dst ----------------
__global__ __launch_bounds__(256) void hist_kernel(const int* __restrict__ dst,
                                                   int* __restrict__ cnt) {
    int e = blockIdx.x * 256 + threadIdx.x;
    if (e < N_EDGES) atomicAdd(&cnt[dst[e]], 1);
}

// ---------------- 3-phase parallel exclusive scan ----------------
__global__ __launch_bounds__(SCAN_B) void reduce_kernel(const int* __restrict__ cnt,
                                                        int* __restrict__ blocksum) {
    __shared__ int red[SCAN_B / 64];
    int idx = blockIdx.x * SCAN_B + threadIdx.x;
    int v = (idx < N_NODES) ? cnt[idx] : 0;
    for (int d = 32; d >= 1; d >>= 1) v += __shfl_down(v, d, 64);
    int wid = threadIdx.x >> 6;
    if ((threadIdx.x & 63) == 0) red[wid] = v;
    __syncthreads();
    if (threadIdx.x == 0) {
        int s = 0;
        for (int w = 0; w < SCAN_B / 64; ++w) s += red[w];
        blocksum[blockIdx.x] = s;
    }
}

__global__ __launch_bounds__(64) void scanblk_kernel(int* __restrict__ blocksum) {
    __shared__ int s[64];
    int t = threadIdx.x;
    s[t] = (t < SCAN_NB) ? blocksum[t] : 0;
    __syncthreads();
    if (t == 0) {
        int run = 0;
        for (int i = 0; i < SCAN_NB; ++i) {
            int c = s[i];
            blocksum[i] = run;
            run += c;
        }
    }
}

__global__ __launch_bounds__(SCAN_B) void scanout_kernel(const int* __restrict__ cnt,
                                                         const int* __restrict__ blockoff,
                                                         int* __restrict__ rowptr,
                                                         int* __restrict__ cursor,
                                                         float* __restrict__ dinv) {
    __shared__ int s[SCAN_B];
    int t = threadIdx.x;
    int idx = blockIdx.x * SCAN_B + t;
    int c = (idx < N_NODES) ? cnt[idx] : 0;
    s[t] = c;
    __syncthreads();
    for (int d = 1; d < SCAN_B; d <<= 1) {
        int v = s[t];
        if (t >= d) v += s[t - d];
        __syncthreads();
        s[t] = v;
        __syncthreads();
    }
    if (idx < N_NODES) {
        int excl = blockoff[blockIdx.x] + s[t] - c;
        rowptr[idx] = excl;
        cursor[idx] = excl;
        dinv[idx] = rsqrtf((float)(c + 1));
        if (idx == 0) rowptr[N_NODES] = N_EDGES;
    }
}

// ---------------- scatter edges into CSR + precompute edge weights ----------------
__global__ __launch_bounds__(256) void scatter_kernel(const int* __restrict__ src,
                                                      const int* __restrict__ dst,
                                                      int* __restrict__ cursor,
                                                      const float* __restrict__ dinv,
                                                      int* __restrict__ ssrc,
                                                      float* __restrict__ wt) {
    int e = blockIdx.x * 256 + threadIdx.x;
    if (e < N_EDGES) {
        int sN = src[e];
        int d = dst[e];
        int pos = atomicAdd(&cursor[d], 1);
        ssrc[pos] = sN;
        wt[pos] = dinv[sN] * dinv[d];
    }
}

// ---------------- Ybf[n,128](bf16) = X[n,128] @ W[128,128] via MFMA ----------------
#define LDK 136   // padded LDS row stride in shorts
__global__ __launch_bounds__(256) void mm_mfma_kernel(const float* __restrict__ X,
                                                      const float* __restrict__ W,
                                                      unsigned short* __restrict__ Y,
                                                      int nrows) {
    __shared__ __align__(16) unsigned short Xs[128 * LDK];
    __shared__ __align__(16) unsigned short Wt[128 * LDK];
    int t = threadIdx.x;

    // stage W transposed: Wt[c][k] = bf16(W[k][c])
    for (int idx = t; idx < 128 * 128; idx += 256) {
        int k = idx >> 7, c = idx & 127;
        Wt[c * LDK + k] = f2bf(W[idx]);
    }
    // stage X tile rows [r0, r0+128) as bf16
    int r0 = blockIdx.x * 128;
    const float4* X4 = (const float4*)X;
    for (int idx = t; idx < 128 * 32; idx += 256) {
        int r = idx >> 5, q = idx & 31;
        int gr = r0 + r;
        float4 vv = (gr < nrows) ? X4[(size_t)gr * 32 + q] : make_float4(0.f, 0.f, 0.f, 0.f);
        int base = r * LDK + q * 4;
        Xs[base + 0] = f2bf(vv.x);
        Xs[base + 1] = f2bf(vv.y);
        Xs[base + 2] = f2bf(vv.z);
        Xs[base + 3] = f2bf(vv.w);
    }
    __syncthreads();

    int w  = t >> 6;
    int l  = t & 63;
    int lg = l >> 4;
    int lr = l & 15;

    f32x4 acc[2][8];
#pragma unroll
    for (int rs = 0; rs < 2; ++rs)
#pragma unroll
        for (int cs = 0; cs < 8; ++cs) acc[rs][cs] = (f32x4){0.f, 0.f, 0.f, 0.f};

#pragma unroll
    for (int ks = 0; ks < 4; ++ks) {
        int koff = ks * 32 + lg * 8;
        bf16x8 a0 = *(const bf16x8*)&Xs[(w * 32 + 0 + lr) * LDK + koff];
        bf16x8 a1 = *(const bf16x8*)&Xs[(w * 32 + 16 + lr) * LDK + koff];
#pragma unroll
        for (int cs = 0; cs < 8; ++cs) {
            bf16x8 b = *(const bf16x8*)&Wt[(cs * 16 + lr) * LDK + koff];
            acc[0][cs] = __builtin_amdgcn_mfma_f32_16x16x32_bf16(a0, b, acc[0][cs], 0, 0, 0);
            acc[1][cs] = __builtin_amdgcn_mfma_f32_16x16x32_bf16(a1, b, acc[1][cs], 0, 0, 0);
        }
    }

#pragma unroll
    for (int rs = 0; rs < 2; ++rs) {
        int rbase = r0 + w * 32 + rs * 16 + lg * 4;
#pragma unroll
        for (int cs = 0; cs < 8; ++cs) {
            int c = cs * 16 + lr;
#pragma unroll
            for (int reg = 0; reg < 4; ++reg) {
                int r = rbase + reg;
                if (r < nrows) Y[(size_t)r * 128 + c] = f2bf(acc[rs][cs][reg]);
            }
        }
    }
}

// ---------------- aggregation: one wave per node, quarter-wave bf16 rows ----------------
// Row = 128 bf16 = 256 B = 16 lanes x ushort8(16B). 4 edges per wave-load,
// 4-deep unroll -> 16 edges / 4 KB in flight per wave. Weights precomputed
// (wt, CSR order) so the chain is {ssrc,wt} -> H row (one dependent gather).
__global__ __launch_bounds__(256) void agg_kernel(const unsigned short* __restrict__ Hbf,
                                                  const int* __restrict__ rowptr,
                                                  const int* __restrict__ ssrc,
                                                  const float* __restrict__ wt,
                                                  const float* __restrict__ dinv,
                                                  const float* __restrict__ bias,
                                                  float* __restrict__ O) {
    int gw = (int)((blockIdx.x * 256 + threadIdx.x) >> 6);
    if (gw >= N_NODES) return;
    int v = __builtin_amdgcn_readfirstlane(gw);
    int lane = threadIdx.x & 63;
    int q = lane >> 4;          // quarter: which edge in a group of 4
    int f = lane & 15;          // 16-B chunk within the 256-B row
    const u16x8* H8 = (const u16x8*)Hbf;   // row stride 16
    float a0 = 0.f, a1 = 0.f, a2 = 0.f, a3 = 0.f,
          a4 = 0.f, a5 = 0.f, a6 = 0.f, a7 = 0.f;
    int e0 = rowptr[v], eend = rowptr[v + 1];
    for (int base = e0; base < eend; base += 16) {
#pragma unroll
        for (int k = 0; k < 4; ++k) {
            int ee = base + 4 * k + q;
            bool inb = ee < eend;
            int ec = inb ? ee : e0;
            int s = ssrc[ec];
            float w = inb ? wt[ec] : 0.f;
            u16x8 h = H8[(size_t)s * 16 + f];
            a0 += w * bf2f(h[0]);
            a1 += w * bf2f(h[1]);
            a2 += w * bf2f(h[2]);
            a3 += w * bf2f(h[3]);
            a4 += w * bf2f(h[4]);
            a5 += w * bf2f(h[5]);
            a6 += w * bf2f(h[6]);
            a7 += w * bf2f(h[7]);
        }
    }
    a0 += __shfl_xor(a0, 16, 64); a0 += __shfl_xor(a0, 32, 64);
    a1 += __shfl_xor(a1, 16, 64); a1 += __shfl_xor(a1, 32, 64);
    a2 += __shfl_xor(a2, 16, 64); a2 += __shfl_xor(a2, 32, 64);
    a3 += __shfl_xor(a3, 16, 64); a3 += __shfl_xor(a3, 32, 64);
    a4 += __shfl_xor(a4, 16, 64); a4 += __shfl_xor(a4, 32, 64);
    a5 += __shfl_xor(a5, 16, 64); a5 += __shfl_xor(a5, 32, 64);
    a6 += __shfl_xor(a6, 16, 64); a6 += __shfl_xor(a6, 32, 64);
    a7 += __shfl_xor(a7, 16, 64); a7 += __shfl_xor(a7, 32, 64);
    if (q == 0) {
        float dv = dinv[v];
        float sc = dv * dv;
        u16x8 hs = H8[(size_t)v * 16 + f];
        float4 b4a = ((const float4*)bias)[f * 2 + 0];
        float4 b4b = ((const float4*)bias)[f * 2 + 1];
        float4 oa, ob;
        oa.x = fmaxf(a0 + sc * bf2f(hs[0]) + b4a.x, 0.f);
        oa.y = fmaxf(a1 + sc * bf2f(hs[1]) + b4a.y, 0.f);
        oa.z = fmaxf(a2 + sc * bf2f(hs[2]) + b4a.z, 0.f);
        oa.w = fmaxf(a3 + sc * bf2f(hs[3]) + b4a.w, 0.f);
        ob.x = fmaxf(a4 + sc * bf2f(hs[4]) + b4b.x, 0.f);
        ob.y = fmaxf(a5 + sc * bf2f(hs[5]) + b4b.y, 0.f);
        ob.z = fmaxf(a6 + sc * bf2f(hs[6]) + b4b.z, 0.f);
        ob.w = fmaxf(a7 + sc * bf2f(hs[7]) + b4b.w, 0.f);
        float4* O4 = (float4*)O;
        O4[(size_t)v * 32 + f * 2 + 0] = oa;
        O4[(size_t)v * 32 + f * 2 + 1] = ob;
    }
}

// ---------------- mean pool per graph (batch is sorted) ----------------
__device__ __forceinline__ int lbound(const int* __restrict__ a, int n, int v) {
    int lo = 0, hi = n;
    while (lo < hi) {
        int mid = (lo + hi) >> 1;
        if (a[mid] < v) lo = mid + 1; else hi = mid;
    }
    return lo;
}

__global__ __launch_bounds__(512) void pool_kernel(const float* __restrict__ H,
                                                   const int* __restrict__ batch,
                                                   float* __restrict__ P) {
    int g = blockIdx.x;
    __shared__ int sse[2];
    __shared__ float red[512];
    if (threadIdx.x < 2) sse[threadIdx.x] = lbound(batch, N_NODES, g + threadIdx.x);
    __syncthreads();
    int ss = sse[0], se = sse[1];
    int d = threadIdx.x & 127, c = threadIdx.x >> 7;
    float sum = 0.f;
    for (int n = ss + c; n < se; n += 4) sum += H[(size_t)n * 128 + d];
    red[threadIdx.x] = sum;
    __syncthreads();
    if (threadIdx.x < 128) {
        float s = red[threadIdx.x] + red[threadIdx.x + 128] + red[threadIdx.x + 256] + red[threadIdx.x + 384];
        float cntf = (float)(se - ss);
        P[g * 128 + threadIdx.x] = s / fmaxf(cntf, 1.f);
    }
}

// ---------------- MLP + log_softmax ----------------
__global__ __launch_bounds__(128) void mlp_kernel(const float* __restrict__ P1,
                                                  const float* __restrict__ P2,
                                                  const float* __restrict__ L1W,
                                                  const float* __restrict__ L1b,
                                                  const float* __restrict__ L2W,
                                                  const float* __restrict__ L2b,
                                                  float* __restrict__ out) {
    int g = blockIdx.x, j = threadIdx.x;
    __shared__ float gv[256];
    __shared__ float hid[128];
    gv[j] = P1[g * 128 + j];
    gv[128 + j] = P2[g * 128 + j];
    __syncthreads();
    float acc = L1b[j];
#pragma unroll 8
    for (int k = 0; k < 256; ++k) acc = fmaf(gv[k], L1W[k * 128 + j], acc);
    hid[j] = fmaxf(acc, 0.f);
    __syncthreads();
    if (j == 0) {
        float o0 = L2b[0], o1 = L2b[1];
        for (int k = 0; k < 128; ++k) {
            o0 += hid[k] * L2W[2 * k + 0];
            o1 += hid[k] * L2W[2 * k + 1];
        }
        float m = fmaxf(o0, o1);
        float lse = m + logf(expf(o0 - m) + expf(o1 - m));
        out[g * 2 + 0] = o0 - lse;
        out[g * 2 + 1] = o1 - lse;
    }
}

extern "C" void kernel_launch(void* const* d_in, const int* in_sizes, int n_in,
                              void* d_out, int out_size, void* d_ws, size_t ws_size,
                              hipStream_t stream) {
    const float* x    = (const float*)d_in[0];
    const int*   ei   = (const int*)d_in[1];    // [2, N_EDGES]: src row then dst row
    const int*   batch= (const int*)d_in[2];
    const float* W1   = (const float*)d_in[3];
    const float* b1   = (const float*)d_in[4];
    const float* W2   = (const float*)d_in[5];
    const float* b2   = (const float*)d_in[6];
    const float* L1W  = (const float*)d_in[7];
    const float* L1b  = (const float*)d_in[8];
    const float* L2W  = (const float*)d_in[9];
    const float* L2b  = (const float*)d_in[10];
    float* out = (float*)d_out;

    const int* e_src = ei;
    const int* e_dst = ei + N_EDGES;

    char* ws = (char*)d_ws;
    size_t off = 0;
    auto alloc = [&](size_t bytes) {
        void* p = ws + off;
        off += (bytes + 255) & ~(size_t)255;
        return p;
    };
    int*   deg_cnt   = (int*)alloc(N_NODES * 4);
    int*   rowptr    = (int*)alloc((N_NODES + 1) * 4);
    int*   cursor    = (int*)alloc(N_NODES * 4);
    int*   ssrc      = (int*)alloc(N_EDGES * 4);
    float* wt        = (float*)alloc(N_EDGES * 4);
    float* dinv      = (float*)alloc(N_NODES * 4);
    int*   blocksum  = (int*)alloc(SCAN_NB * 4);
    float* p1        = (float*)alloc(N_GRAPHS * DIM * 4);
    float* p2        = (float*)alloc(N_GRAPHS * DIM * 4);
    unsigned short* bufBf = (unsigned short*)alloc((size_t)N_NODES * DIM * 2);
    float* bufB      = (float*)alloc((size_t)N_NODES * DIM * 4);
    (void)ws_size; (void)in_sizes; (void)n_in; (void)out_size;

    hipMemsetAsync(deg_cnt, 0, N_NODES * 4, stream);

    const int EB = (N_EDGES + 255) / 256;      // 3125
    hist_kernel<<<EB, 256, 0, stream>>>(e_dst, deg_cnt);
    reduce_kernel<<<SCAN_NB, SCAN_B, 0, stream>>>(deg_cnt, blocksum);
    scanblk_kernel<<<1, 64, 0, stream>>>(blocksum);
    scanout_kernel<<<SCAN_NB, SCAN_B, 0, stream>>>(deg_cnt, blocksum, rowptr, cursor, dinv);
    scatter_kernel<<<EB, 256, 0, stream>>>(e_src, e_dst, cursor, dinv, ssrc, wt);

    const int MMB = (N_NODES + 127) / 128;      // 391
    const int AGB = (N_NODES * 64 + 255) / 256; // 12500

    // conv1
    mm_mfma_kernel<<<MMB, 256, 0, stream>>>(x, W1, bufBf, N_NODES);
    agg_kernel<<<AGB, 256, 0, stream>>>(bufBf, rowptr, ssrc, wt, dinv, b1, bufB);  // h1 (fp32)
    pool_kernel<<<N_GRAPHS, 512, 0, stream>>>(bufB, batch, p1);

    // conv2
    mm_mfma_kernel<<<MMB, 256, 0, stream>>>(bufB, W2, bufBf, N_NODES);
    agg_kernel<<<AGB, 256, 0, stream>>>(bufBf, rowptr, ssrc, wt, dinv, b2, bufB);  // h2
    pool_kernel<<<N_GRAPHS, 512, 0, stream>>>(bufB, batch, p2);

    // head
    mlp_kernel<<<N_GRAPHS, 128, 0, stream>>>(p1, p2, L1W, L1b, L2W, L2b, out);
}

// Round 11
// 323.615 us; speedup vs baseline: 2.4022x; 1.0313x over previous
//
#include <hip/hip_runtime.h>

#define N_NODES 50000
#define N_EDGES 800000
#define N_GRAPHS 256
#define DIM 128

#define SCAN_B 1024
#define SCAN_NB 49   // ceil(50000/1024)

typedef __attribute__((ext_vector_type(8))) short bf16x8;
typedef __attribute__((ext_vector_type(4))) float f32x4;
typedef __attribute__((ext_vector_type(8))) unsigned short u16x8;

__device__ __forceinline__ unsigned short f2bf(float f) {
    union { float f; unsigned u; } v; v.f = f;
    unsigned u = v.u;
    u += 0x7fffu + ((u >> 16) & 1u);   // round-to-nearest-even
    return (unsigned short)(u >> 16);
}
__device__ __forceinline__ float bf2f(unsigned short h) {
    union { unsigned u; float f; } v; v.u = ((unsigned)h) << 16;
    return v.f;
}

// ---------------- histogram of dst ----------------
__global__ __launch_bounds__(256) void hist_kernel(const int* __restrict__ dst,
                                                   int* __restrict__ cnt) {
    int e = blockIdx.x * 256 + threadIdx.x;
    if (e < N_EDGES) atomicAdd(&cnt[dst[e]], 1);
}

// ---------------- 3-phase parallel exclusive scan ----------------
__global__ __launch_bounds__(SCAN_B) void reduce_kernel(const int* __restrict__ cnt,
                                                        int* __restrict__ blocksum) {
    __shared__ int red[SCAN_B / 64];
    int idx = blockIdx.x * SCAN_B + threadIdx.x;
    int v = (idx < N_NODES) ? cnt[idx] : 0;
    for (int d = 32; d >= 1; d >>= 1) v += __shfl_down(v, d, 64);
    int wid = threadIdx.x >> 6;
    if ((threadIdx.x & 63) == 0) red[wid] = v;
    __syncthreads();
    if (threadIdx.x == 0) {
        int s = 0;
        for (int w = 0; w < SCAN_B / 64; ++w) s += red[w];
        blocksum[blockIdx.x] = s;
    }
}

__global__ __launch_bounds__(64) void scanblk_kernel(int* __restrict__ blocksum) {
    __shared__ int s[64];
    int t = threadIdx.x;
    s[t] = (t < SCAN_NB) ? blocksum[t] : 0;
    __syncthreads();
    if (t == 0) {
        int run = 0;
        for (int i = 0; i < SCAN_NB; ++i) {
            int c = s[i];
            blocksum[i] = run;
            run += c;
        }
    }
}

__global__ __launch_bounds__(SCAN_B) void scanout_kernel(const int* __restrict__ cnt,
                                                         const int* __restrict__ blockoff,
                                                         int* __restrict__ rowptr,
                                                         int* __restrict__ cursor,
                                                         float* __restrict__ dinv) {
    __shared__ int s[SCAN_B];
    int t = threadIdx.x;
    int idx = blockIdx.x * SCAN_B + t;
    int c = (idx < N_NODES) ? cnt[idx] : 0;
    s[t] = c;
    __syncthreads();
    for (int d = 1; d < SCAN_B; d <<= 1) {
        int v = s[t];
        if (t >= d) v += s[t - d];
        __syncthreads();
        s[t] = v;
        __syncthreads();
    }
    if (idx < N_NODES) {
        int excl = blockoff[blockIdx.x] + s[t] - c;
        rowptr[idx] = excl;
        cursor[idx] = excl;
        dinv[idx] = rsqrtf((float)(c + 1));
        if (idx == 0) rowptr[N_NODES] = N_EDGES;
    }
}

// ---------------- scatter edges into CSR: packed {src, w} 8B record ----------------
__global__ __launch_bounds__(256) void scatter_kernel(const int* __restrict__ src,
                                                      const int* __restrict__ dst,
                                                      int* __restrict__ cursor,
                                                      const float* __restrict__ dinv,
                                                      int2* __restrict__ sedge) {
    int e = blockIdx.x * 256 + threadIdx.x;
    if (e < N_EDGES) {
        int sN = src[e];
        int d = dst[e];
        int pos = atomicAdd(&cursor[d], 1);
        int2 rec;
        rec.x = sN;
        rec.y = __float_as_int(dinv[sN] * dinv[d]);
        sedge[pos] = rec;
    }
}

// ---------------- Ybf[n,128](bf16) = X[n,128] @ W[128,128] via MFMA ----------------
#define LDK 136   // padded LDS row stride in shorts
__global__ __launch_bounds__(256) void mm_mfma_kernel(const float* __restrict__ X,
                                                      const float* __restrict__ W,
                                                      unsigned short* __restrict__ Y,
                                                      int nrows) {
    __shared__ __align__(16) unsigned short Xs[128 * LDK];
    __shared__ __align__(16) unsigned short Wt[128 * LDK];
    int t = threadIdx.x;

    // stage W transposed: Wt[c][k] = bf16(W[k][c])
    for (int idx = t; idx < 128 * 128; idx += 256) {
        int k = idx >> 7, c = idx & 127;
        Wt[c * LDK + k] = f2bf(W[idx]);
    }
    // stage X tile rows [r0, r0+128) as bf16
    int r0 = blockIdx.x * 128;
    const float4* X4 = (const float4*)X;
    for (int idx = t; idx < 128 * 32; idx += 256) {
        int r = idx >> 5, q = idx & 31;
        int gr = r0 + r;
        float4 vv = (gr < nrows) ? X4[(size_t)gr * 32 + q] : make_float4(0.f, 0.f, 0.f, 0.f);
        int base = r * LDK + q * 4;
        Xs[base + 0] = f2bf(vv.x);
        Xs[base + 1] = f2bf(vv.y);
        Xs[base + 2] = f2bf(vv.z);
        Xs[base + 3] = f2bf(vv.w);
    }
    __syncthreads();

    int w  = t >> 6;
    int l  = t & 63;
    int lg = l >> 4;
    int lr = l & 15;

    f32x4 acc[2][8];
#pragma unroll
    for (int rs = 0; rs < 2; ++rs)
#pragma unroll
        for (int cs = 0; cs < 8; ++cs) acc[rs][cs] = (f32x4){0.f, 0.f, 0.f, 0.f};

#pragma unroll
    for (int ks = 0; ks < 4; ++ks) {
        int koff = ks * 32 + lg * 8;
        bf16x8 a0 = *(const bf16x8*)&Xs[(w * 32 + 0 + lr) * LDK + koff];
        bf16x8 a1 = *(const bf16x8*)&Xs[(w * 32 + 16 + lr) * LDK + koff];
#pragma unroll
        for (int cs = 0; cs < 8; ++cs) {
            bf16x8 b = *(const bf16x8*)&Wt[(cs * 16 + lr) * LDK + koff];
            acc[0][cs] = __builtin_amdgcn_mfma_f32_16x16x32_bf16(a0, b, acc[0][cs], 0, 0, 0);
            acc[1][cs] = __builtin_amdgcn_mfma_f32_16x16x32_bf16(a1, b, acc[1][cs], 0, 0, 0);
        }
    }

#pragma unroll
    for (int rs = 0; rs < 2; ++rs) {
        int rbase = r0 + w * 32 + rs * 16 + lg * 4;
#pragma unroll
        for (int cs = 0; cs < 8; ++cs) {
            int c = cs * 16 + lr;
#pragma unroll
            for (int reg = 0; reg < 4; ++reg) {
                int r = rbase + reg;
                if (r < nrows) Y[(size_t)r * 128 + c] = f2bf(acc[rs][cs][reg]);
            }
        }
    }
}

// ---------------- aggregation: one wave per node, quarter-wave bf16 rows ----------------
// Row = 128 bf16 = 256 B = 16 lanes x ushort8(16B). 4 edges per wave-load,
// 4-deep unroll -> 16 edges / 4 KB in flight per wave. Edge record packed
// {src, w} so the chain is one 8B load -> H row gather.
__global__ __launch_bounds__(256) void agg_kernel(const unsigned short* __restrict__ Hbf,
                                                  const int* __restrict__ rowptr,
                                                  const int2* __restrict__ sedge,
                                                  const float* __restrict__ dinv,
                                                  const float* __restrict__ bias,
                                                  float* __restrict__ O) {
    int gw = (int)((blockIdx.x * 256 + threadIdx.x) >> 6);
    if (gw >= N_NODES) return;
    int v = __builtin_amdgcn_readfirstlane(gw);
    int lane = threadIdx.x & 63;
    int q = lane >> 4;          // quarter: which edge in a group of 4
    int f = lane & 15;          // 16-B chunk within the 256-B row
    const u16x8* H8 = (const u16x8*)Hbf;   // row stride 16
    float a0 = 0.f, a1 = 0.f, a2 = 0.f, a3 = 0.f,
          a4 = 0.f, a5 = 0.f, a6 = 0.f, a7 = 0.f;
    int e0 = rowptr[v], eend = rowptr[v + 1];
    for (int base = e0; base < eend; base += 16) {
#pragma unroll
        for (int k = 0; k < 4; ++k) {
            int ee = base + 4 * k + q;
            bool inb = ee < eend;
            int ec = inb ? ee : e0;
            int2 rec = sedge[ec];
            int s = rec.x;
            float w = inb ? __int_as_float(rec.y) : 0.f;
            u16x8 h = H8[(size_t)s * 16 + f];
            a0 += w * bf2f(h[0]);
            a1 += w * bf2f(h[1]);
            a2 += w * bf2f(h[2]);
            a3 += w * bf2f(h[3]);
            a4 += w * bf2f(h[4]);
            a5 += w * bf2f(h[5]);
            a6 += w * bf2f(h[6]);
            a7 += w * bf2f(h[7]);
        }
    }
    a0 += __shfl_xor(a0, 16, 64); a0 += __shfl_xor(a0, 32, 64);
    a1 += __shfl_xor(a1, 16, 64); a1 += __shfl_xor(a1, 32, 64);
    a2 += __shfl_xor(a2, 16, 64); a2 += __shfl_xor(a2, 32, 64);
    a3 += __shfl_xor(a3, 16, 64); a3 += __shfl_xor(a3, 32, 64);
    a4 += __shfl_xor(a4, 16, 64); a4 += __shfl_xor(a4, 32, 64);
    a5 += __shfl_xor(a5, 16, 64); a5 += __shfl_xor(a5, 32, 64);
    a6 += __shfl_xor(a6, 16, 64); a6 += __shfl_xor(a6, 32, 64);
    a7 += __shfl_xor(a7, 16, 64); a7 += __shfl_xor(a7, 32, 64);
    if (q == 0) {
        float dv = dinv[v];
        float sc = dv * dv;
        u16x8 hs = H8[(size_t)v * 16 + f];
        float4 b4a = ((const float4*)bias)[f * 2 + 0];
        float4 b4b = ((const float4*)bias)[f * 2 + 1];
        float4 oa, ob;
        oa.x = fmaxf(a0 + sc * bf2f(hs[0]) + b4a.x, 0.f);
        oa.y = fmaxf(a1 + sc * bf2f(hs[1]) + b4a.y, 0.f);
        oa.z = fmaxf(a2 + sc * bf2f(hs[2]) + b4a.z, 0.f);
        oa.w = fmaxf(a3 + sc * bf2f(hs[3]) + b4a.w, 0.f);
        ob.x = fmaxf(a4 + sc * bf2f(hs[4]) + b4b.x, 0.f);
        ob.y = fmaxf(a5 + sc * bf2f(hs[5]) + b4b.y, 0.f);
        ob.z = fmaxf(a6 + sc * bf2f(hs[6]) + b4b.z, 0.f);
        ob.w = fmaxf(a7 + sc * bf2f(hs[7]) + b4b.w, 0.f);
        float4* O4 = (float4*)O;
        O4[(size_t)v * 32 + f * 2 + 0] = oa;
        O4[(size_t)v * 32 + f * 2 + 1] = ob;
    }
}

// ---------------- mean pool per graph (batch is sorted) ----------------
__device__ __forceinline__ int lbound(const int* __restrict__ a, int n, int v) {
    int lo = 0, hi = n;
    while (lo < hi) {
        int mid = (lo + hi) >> 1;
        if (a[mid] < v) lo = mid + 1; else hi = mid;
    }
    return lo;
}

__global__ __launch_bounds__(512) void pool_kernel(const float* __restrict__ H,
                                                   const int* __restrict__ batch,
                                                   float* __restrict__ P) {
    int g = blockIdx.x;
    __shared__ int sse[2];
    __shared__ float red[512];
    if (threadIdx.x < 2) sse[threadIdx.x] = lbound(batch, N_NODES, g + threadIdx.x);
    __syncthreads();
    int ss = sse[0], se = sse[1];
    int d = threadIdx.x & 127, c = threadIdx.x >> 7;
    float sum = 0.f;
    for (int n = ss + c; n < se; n += 4) sum += H[(size_t)n * 128 + d];
    red[threadIdx.x] = sum;
    __syncthreads();
    if (threadIdx.x < 128) {
        float s = red[threadIdx.x] + red[threadIdx.x + 128] + red[threadIdx.x + 256] + red[threadIdx.x + 384];
        float cntf = (float)(se - ss);
        P[g * 128 + threadIdx.x] = s / fmaxf(cntf, 1.f);
    }
}

// ---------------- MLP + log_softmax ----------------
__global__ __launch_bounds__(128) void mlp_kernel(const float* __restrict__ P1,
                                                  const float* __restrict__ P2,
                                                  const float* __restrict__ L1W,
                                                  const float* __restrict__ L1b,
                                                  const float* __restrict__ L2W,
                                                  const float* __restrict__ L2b,
                                                  float* __restrict__ out) {
    int g = blockIdx.x, j = threadIdx.x;
    __shared__ float gv[256];
    __shared__ float hid[128];
    gv[j] = P1[g * 128 + j];
    gv[128 + j] = P2[g * 128 + j];
    __syncthreads();
    float acc = L1b[j];
#pragma unroll 8
    for (int k = 0; k < 256; ++k) acc = fmaf(gv[k], L1W[k * 128 + j], acc);
    hid[j] = fmaxf(acc, 0.f);
    __syncthreads();
    if (j == 0) {
        float o0 = L2b[0], o1 = L2b[1];
        for (int k = 0; k < 128; ++k) {
            o0 += hid[k] * L2W[2 * k + 0];
            o1 += hid[k] * L2W[2 * k + 1];
        }
        float m = fmaxf(o0, o1);
        float lse = m + logf(expf(o0 - m) + expf(o1 - m));
        out[g * 2 + 0] = o0 - lse;
        out[g * 2 + 1] = o1 - lse;
    }
}

extern "C" void kernel_launch(void* const* d_in, const int* in_sizes, int n_in,
                              void* d_out, int out_size, void* d_ws, size_t ws_size,
                              hipStream_t stream) {
    const float* x    = (const float*)d_in[0];
    const int*   ei   = (const int*)d_in[1];    // [2, N_EDGES]: src row then dst row
    const int*   batch= (const int*)d_in[2];
    const float* W1   = (const float*)d_in[3];
    const float* b1   = (const float*)d_in[4];
    const float* W2   = (const float*)d_in[5];
    const float* b2   = (const float*)d_in[6];
    const float* L1W  = (const float*)d_in[7];
    const float* L1b  = (const float*)d_in[8];
    const float* L2W  = (const float*)d_in[9];
    const float* L2b  = (const float*)d_in[10];
    float* out = (float*)d_out;

    const int* e_src = ei;
    const int* e_dst = ei + N_EDGES;

    char* ws = (char*)d_ws;
    size_t off = 0;
    auto alloc = [&](size_t bytes) {
        void* p = ws + off;
        off += (bytes + 255) & ~(size_t)255;
        return p;
    };
    int*   deg_cnt   = (int*)alloc(N_NODES * 4);
    int*   rowptr    = (int*)alloc((N_NODES + 1) * 4);
    int*   cursor    = (int*)alloc(N_NODES * 4);
    int2*  sedge     = (int2*)alloc((size_t)N_EDGES * 8);
    float* dinv      = (float*)alloc(N_NODES * 4);
    int*   blocksum  = (int*)alloc(SCAN_NB * 4);
    float* p1        = (float*)alloc(N_GRAPHS * DIM * 4);
    float* p2        = (float*)alloc(N_GRAPHS * DIM * 4);
    unsigned short* bufBf = (unsigned short*)alloc((size_t)N_NODES * DIM * 2);
    float* bufB      = (float*)alloc((size_t)N_NODES * DIM * 4);
    (void)ws_size; (void)in_sizes; (void)n_in; (void)out_size;

    hipMemsetAsync(deg_cnt, 0, N_NODES * 4, stream);

    const int EB = (N_EDGES + 255) / 256;      // 3125
    hist_kernel<<<EB, 256, 0, stream>>>(e_dst, deg_cnt);
    reduce_kernel<<<SCAN_NB, SCAN_B, 0, stream>>>(deg_cnt, blocksum);
    scanblk_kernel<<<1, 64, 0, stream>>>(blocksum);
    scanout_kernel<<<SCAN_NB, SCAN_B, 0, stream>>>(deg_cnt, blocksum, rowptr, cursor, dinv);
    scatter_kernel<<<EB, 256, 0, stream>>>(e_src, e_dst, cursor, dinv, sedge);

    const int MMB = (N_NODES + 127) / 128;      // 391
    const int AGB = (N_NODES * 64 + 255) / 256; // 12500

    // conv1
    mm_mfma_kernel<<<MMB, 256, 0, stream>>>(x, W1, bufBf, N_NODES);
    agg_kernel<<<AGB, 256, 0, stream>>>(bufBf, rowptr, sedge, dinv, b1, bufB);  // h1 (fp32)
    pool_kernel<<<N_GRAPHS, 512, 0, stream>>>(bufB, batch, p1);

    // conv2
    mm_mfma_kernel<<<MMB, 256, 0, stream>>>(bufB, W2, bufBf, N_NODES);
    agg_kernel<<<AGB, 256, 0, stream>>>(bufBf, rowptr, sedge, dinv, b2, bufB);  // h2
    pool_kernel<<<N_GRAPHS, 512, 0, stream>>>(bufB, batch, p2);

    // head
    mlp_kernel<<<N_GRAPHS, 128, 0, stream>>>(p1, p2, L1W, L1b, L2W, L2b, out);
}

// Round 12
// 274.996 us; speedup vs baseline: 2.8269x; 1.1768x over previous
//
#include <hip/hip_runtime.h>

#define N_NODES 50000
#define N_EDGES 800000
#define N_GRAPHS 256
#define DIM 128

// ---- two-level counting sort geometry ----
#define NBUCK 196          // ceil(50000/256), bucket = dst >> 8
#define A_BLOCKS 200
#define A_EPB 4000         // 200 * 4000 = 800000 edges exactly
#define N_SEG (NBUCK * A_BLOCKS)   // 39200 (bucket-major)
#define SCANA_B 1024
#define SCANA_NB 39        // ceil(39200/1024)

typedef __attribute__((ext_vector_type(8))) short bf16x8;
typedef __attribute__((ext_vector_type(4))) float f32x4;
typedef __attribute__((ext_vector_type(8))) unsigned short u16x8;

__device__ __forceinline__ unsigned short f2bf(float f) {
    union { float f; unsigned u; } v; v.f = f;
    unsigned u = v.u;
    u += 0x7fffu + ((u >> 16) & 1u);   // round-to-nearest-even
    return (unsigned short)(u >> 16);
}
__device__ __forceinline__ float bf2f(unsigned short h) {
    union { unsigned u; float f; } v; v.u = ((unsigned)h) << 16;
    return v.f;
}

// ---------------- A1: per-(bucket, ablock) counts ----------------
__global__ __launch_bounds__(256) void a1_count_kernel(const int* __restrict__ dst,
                                                       int* __restrict__ cntA) {
    __shared__ int hist[NBUCK];
    int t = threadIdx.x;
    for (int b = t; b < NBUCK; b += 256) hist[b] = 0;
    __syncthreads();
    int base = blockIdx.x * A_EPB;
    for (int i = t; i < A_EPB; i += 256) {
        int d = dst[base + i];
        atomicAdd(&hist[d >> 8], 1);
    }
    __syncthreads();
    for (int b = t; b < NBUCK; b += 256) cntA[b * A_BLOCKS + blockIdx.x] = hist[b];
}

// ---------------- 3-phase exclusive scan over N_SEG ----------------
__global__ __launch_bounds__(SCANA_B) void reduceN_kernel(const int* __restrict__ in,
                                                          int* __restrict__ bsum) {
    __shared__ int red[SCANA_B / 64];
    int idx = blockIdx.x * SCANA_B + threadIdx.x;
    int v = (idx < N_SEG) ? in[idx] : 0;
    for (int d = 32; d >= 1; d >>= 1) v += __shfl_down(v, d, 64);
    if ((threadIdx.x & 63) == 0) red[threadIdx.x >> 6] = v;
    __syncthreads();
    if (threadIdx.x == 0) {
        int s = 0;
        for (int w = 0; w < SCANA_B / 64; ++w) s += red[w];
        bsum[blockIdx.x] = s;
    }
}

__global__ __launch_bounds__(64) void scanblkN_kernel(int* __restrict__ bsum) {
    if (threadIdx.x == 0) {
        int run = 0;
        for (int i = 0; i < SCANA_NB; ++i) { int c = bsum[i]; bsum[i] = run; run += c; }
    }
}

__global__ __launch_bounds__(SCANA_B) void scanoutN_kernel(const int* __restrict__ in,
                                                           const int* __restrict__ boff,
                                                           int* __restrict__ outx) {
    __shared__ int s[SCANA_B];
    int t = threadIdx.x;
    int idx = blockIdx.x * SCANA_B + t;
    int c = (idx < N_SEG) ? in[idx] : 0;
    s[t] = c;
    __syncthreads();
    for (int d = 1; d < SCANA_B; d <<= 1) {
        int v = s[t];
        if (t >= d) v += s[t - d];
        __syncthreads();
        s[t] = v;
        __syncthreads();
    }
    if (idx < N_SEG) outx[idx] = boff[blockIdx.x] + s[t] - c;   // exclusive
}

// ---------------- A2: scatter into bucket-segmented {src,dst} ----------------
// Each (blk,bucket) segment is contiguous and written only by this block (one CU)
// -> XCD L2 merges the 8B writes into full lines.
__global__ __launch_bounds__(256) void a2_scatter_kernel(const int* __restrict__ src,
                                                         const int* __restrict__ dst,
                                                         const int* __restrict__ baseA,
                                                         int2* __restrict__ ebuf) {
    __shared__ int cur[NBUCK];
    int t = threadIdx.x;
    for (int b = t; b < NBUCK; b += 256) cur[b] = baseA[b * A_BLOCKS + blockIdx.x];
    __syncthreads();
    int base = blockIdx.x * A_EPB;
    for (int i = t; i < A_EPB; i += 256) {
        int e = base + i;
        int sN = src[e], d = dst[e];
        int pos = atomicAdd(&cur[d >> 8], 1);
        int2 r; r.x = sN; r.y = d;
        ebuf[pos] = r;
    }
}

// ---------------- B: per-bucket counting sort -> CSR + rowptr + dinv ----------------
__global__ __launch_bounds__(512) void bucket_kernel(const int2* __restrict__ ebuf,
                                                     const int* __restrict__ baseA,
                                                     int2* __restrict__ sedge,
                                                     int* __restrict__ rowptr,
                                                     float* __restrict__ dinv) {
    int b = blockIdx.x;
    int t = threadIdx.x;
    __shared__ int cnt[256], sc[256], cur[256];
    __shared__ int se[2];
    if (t == 0) {
        se[0] = baseA[b * A_BLOCKS];
        se[1] = (b + 1 < NBUCK) ? baseA[(b + 1) * A_BLOCKS] : N_EDGES;
    }
    if (t < 256) cnt[t] = 0;
    __syncthreads();
    int start = se[0], end = se[1];
    for (int i = start + t; i < end; i += 512) atomicAdd(&cnt[ebuf[i].y & 255], 1);
    __syncthreads();
    if (t < 256) sc[t] = cnt[t];
    __syncthreads();
    for (int d = 1; d < 256; d <<= 1) {
        int v = 0;
        if (t < 256) { v = sc[t]; if (t >= d) v += sc[t - d]; }
        __syncthreads();
        if (t < 256) sc[t] = v;
        __syncthreads();
    }
    if (t < 256) {
        int excl = start + sc[t] - cnt[t];
        cur[t] = excl;
        int v = b * 256 + t;
        if (v < N_NODES) {
            rowptr[v] = excl;
            dinv[v] = rsqrtf((float)(cnt[t] + 1));
        }
    }
    if (b == 0 && t == 0) rowptr[N_NODES] = N_EDGES;
    __syncthreads();
    // final scatter: whole bucket region is one contiguous ~32KB window, single CU
    for (int i = start + t; i < end; i += 512) {
        int2 r = ebuf[i];
        int pos = atomicAdd(&cur[r.y & 255], 1);
        sedge[pos] = r;   // {src, dst} for now; weights filled by weight_kernel
    }
}

// ---------------- C: in-place {src,dst} -> {src, w} ----------------
__global__ __launch_bounds__(512) void weight_kernel(int2* __restrict__ sedge,
                                                     const float* __restrict__ dinv) {
    int i = blockIdx.x * 512 + threadIdx.x;
    if (i < N_EDGES) {
        int2 r = sedge[i];
        float w = dinv[r.x] * dinv[r.y];
        r.y = __float_as_int(w);
        sedge[i] = r;
    }
}

// ---------------- Ybf[n,128](bf16) = X[n,128] @ W[128,128] via MFMA ----------------
#define LDK 136   // padded LDS row stride in shorts
__global__ __launch_bounds__(256) void mm_mfma_kernel(const float* __restrict__ X,
                                                      const float* __restrict__ W,
                                                      unsigned short* __restrict__ Y,
                                                      int nrows) {
    __shared__ __align__(16) unsigned short Xs[128 * LDK];
    __shared__ __align__(16) unsigned short Wt[128 * LDK];
    int t = threadIdx.x;

    // stage W transposed: Wt[c][k] = bf16(W[k][c])
    for (int idx = t; idx < 128 * 128; idx += 256) {
        int k = idx >> 7, c = idx & 127;
        Wt[c * LDK + k] = f2bf(W[idx]);
    }
    // stage X tile rows [r0, r0+128) as bf16
    int r0 = blockIdx.x * 128;
    const float4* X4 = (const float4*)X;
    for (int idx = t; idx < 128 * 32; idx += 256) {
        int r = idx >> 5, q = idx & 31;
        int gr = r0 + r;
        float4 vv = (gr < nrows) ? X4[(size_t)gr * 32 + q] : make_float4(0.f, 0.f, 0.f, 0.f);
        int base = r * LDK + q * 4;
        Xs[base + 0] = f2bf(vv.x);
        Xs[base + 1] = f2bf(vv.y);
        Xs[base + 2] = f2bf(vv.z);
        Xs[base + 3] = f2bf(vv.w);
    }
    __syncthreads();

    int w  = t >> 6;
    int l  = t & 63;
    int lg = l >> 4;
    int lr = l & 15;

    f32x4 acc[2][8];
#pragma unroll
    for (int rs = 0; rs < 2; ++rs)
#pragma unroll
        for (int cs = 0; cs < 8; ++cs) acc[rs][cs] = (f32x4){0.f, 0.f, 0.f, 0.f};

#pragma unroll
    for (int ks = 0; ks < 4; ++ks) {
        int koff = ks * 32 + lg * 8;
        bf16x8 a0 = *(const bf16x8*)&Xs[(w * 32 + 0 + lr) * LDK + koff];
        bf16x8 a1 = *(const bf16x8*)&Xs[(w * 32 + 16 + lr) * LDK + koff];
#pragma unroll
        for (int cs = 0; cs < 8; ++cs) {
            bf16x8 b = *(const bf16x8*)&Wt[(cs * 16 + lr) * LDK + koff];
            acc[0][cs] = __builtin_amdgcn_mfma_f32_16x16x32_bf16(a0, b, acc[0][cs], 0, 0, 0);
            acc[1][cs] = __builtin_amdgcn_mfma_f32_16x16x32_bf16(a1, b, acc[1][cs], 0, 0, 0);
        }
    }

#pragma unroll
    for (int rs = 0; rs < 2; ++rs) {
        int rbase = r0 + w * 32 + rs * 16 + lg * 4;
#pragma unroll
        for (int cs = 0; cs < 8; ++cs) {
            int c = cs * 16 + lr;
#pragma unroll
            for (int reg = 0; reg < 4; ++reg) {
                int r = rbase + reg;
                if (r < nrows) Y[(size_t)r * 128 + c] = f2bf(acc[rs][cs][reg]);
            }
        }
    }
}

// ---------------- aggregation: one wave per node, quarter-wave bf16 rows ----------------
__global__ __launch_bounds__(256) void agg_kernel(const unsigned short* __restrict__ Hbf,
                                                  const int* __restrict__ rowptr,
                                                  const int2* __restrict__ sedge,
                                                  const float* __restrict__ dinv,
                                                  const float* __restrict__ bias,
                                                  float* __restrict__ O) {
    int gw = (int)((blockIdx.x * 256 + threadIdx.x) >> 6);
    if (gw >= N_NODES) return;
    int v = __builtin_amdgcn_readfirstlane(gw);
    int lane = threadIdx.x & 63;
    int q = lane >> 4;          // quarter: which edge in a group of 4
    int f = lane & 15;          // 16-B chunk within the 256-B row
    const u16x8* H8 = (const u16x8*)Hbf;   // row stride 16
    float a0 = 0.f, a1 = 0.f, a2 = 0.f, a3 = 0.f,
          a4 = 0.f, a5 = 0.f, a6 = 0.f, a7 = 0.f;
    int e0 = rowptr[v], eend = rowptr[v + 1];
    for (int base = e0; base < eend; base += 16) {
#pragma unroll
        for (int k = 0; k < 4; ++k) {
            int ee = base + 4 * k + q;
            bool inb = ee < eend;
            int ec = inb ? ee : e0;
            int2 rec = sedge[ec];
            int s = rec.x;
            float w = inb ? __int_as_float(rec.y) : 0.f;
            u16x8 h = H8[(size_t)s * 16 + f];
            a0 += w * bf2f(h[0]);
            a1 += w * bf2f(h[1]);
            a2 += w * bf2f(h[2]);
            a3 += w * bf2f(h[3]);
            a4 += w * bf2f(h[4]);
            a5 += w * bf2f(h[5]);
            a6 += w * bf2f(h[6]);
            a7 += w * bf2f(h[7]);
        }
    }
    a0 += __shfl_xor(a0, 16, 64); a0 += __shfl_xor(a0, 32, 64);
    a1 += __shfl_xor(a1, 16, 64); a1 += __shfl_xor(a1, 32, 64);
    a2 += __shfl_xor(a2, 16, 64); a2 += __shfl_xor(a2, 32, 64);
    a3 += __shfl_xor(a3, 16, 64); a3 += __shfl_xor(a3, 32, 64);
    a4 += __shfl_xor(a4, 16, 64); a4 += __shfl_xor(a4, 32, 64);
    a5 += __shfl_xor(a5, 16, 64); a5 += __shfl_xor(a5, 32, 64);
    a6 += __shfl_xor(a6, 16, 64); a6 += __shfl_xor(a6, 32, 64);
    a7 += __shfl_xor(a7, 16, 64); a7 += __shfl_xor(a7, 32, 64);
    if (q == 0) {
        float dv = dinv[v];
        float sc = dv * dv;
        u16x8 hs = H8[(size_t)v * 16 + f];
        float4 b4a = ((const float4*)bias)[f * 2 + 0];
        float4 b4b = ((const float4*)bias)[f * 2 + 1];
        float4 oa, ob;
        oa.x = fmaxf(a0 + sc * bf2f(hs[0]) + b4a.x, 0.f);
        oa.y = fmaxf(a1 + sc * bf2f(hs[1]) + b4a.y, 0.f);
        oa.z = fmaxf(a2 + sc * bf2f(hs[2]) + b4a.z, 0.f);
        oa.w = fmaxf(a3 + sc * bf2f(hs[3]) + b4a.w, 0.f);
        ob.x = fmaxf(a4 + sc * bf2f(hs[4]) + b4b.x, 0.f);
        ob.y = fmaxf(a5 + sc * bf2f(hs[5]) + b4b.y, 0.f);
        ob.z = fmaxf(a6 + sc * bf2f(hs[6]) + b4b.z, 0.f);
        ob.w = fmaxf(a7 + sc * bf2f(hs[7]) + b4b.w, 0.f);
        float4* O4 = (float4*)O;
        O4[(size_t)v * 32 + f * 2 + 0] = oa;
        O4[(size_t)v * 32 + f * 2 + 1] = ob;
    }
}

// ---------------- mean pool per graph (batch is sorted) ----------------
__device__ __forceinline__ int lbound(const int* __restrict__ a, int n, int v) {
    int lo = 0, hi = n;
    while (lo < hi) {
        int mid = (lo + hi) >> 1;
        if (a[mid] < v) lo = mid + 1; else hi = mid;
    }
    return lo;
}

__global__ __launch_bounds__(512) void pool_kernel(const float* __restrict__ H,
                                                   const int* __restrict__ batch,
                                                   float* __restrict__ P) {
    int g = blockIdx.x;
    __shared__ int sse[2];
    __shared__ float red[512];
    if (threadIdx.x < 2) sse[threadIdx.x] = lbound(batch, N_NODES, g + threadIdx.x);
    __syncthreads();
    int ss = sse[0], se = sse[1];
    int d = threadIdx.x & 127, c = threadIdx.x >> 7;
    float sum = 0.f;
    for (int n = ss + c; n < se; n += 4) sum += H[(size_t)n * 128 + d];
    red[threadIdx.x] = sum;
    __syncthreads();
    if (threadIdx.x < 128) {
        float s = red[threadIdx.x] + red[threadIdx.x + 128] + red[threadIdx.x + 256] + red[threadIdx.x + 384];
        float cntf = (float)(se - ss);
        P[g * 128 + threadIdx.x] = s / fmaxf(cntf, 1.f);
    }
}

// ---------------- MLP + log_softmax ----------------
__global__ __launch_bounds__(128) void mlp_kernel(const float* __restrict__ P1,
                                                  const float* __restrict__ P2,
                                                  const float* __restrict__ L1W,
                                                  const float* __restrict__ L1b,
                                                  const float* __restrict__ L2W,
                                                  const float* __restrict__ L2b,
                                                  float* __restrict__ out) {
    int g = blockIdx.x, j = threadIdx.x;
    __shared__ float gv[256];
    __shared__ float hid[128];
    gv[j] = P1[g * 128 + j];
    gv[128 + j] = P2[g * 128 + j];
    __syncthreads();
    float acc = L1b[j];
#pragma unroll 8
    for (int k = 0; k < 256; ++k) acc = fmaf(gv[k], L1W[k * 128 + j], acc);
    hid[j] = fmaxf(acc, 0.f);
    __syncthreads();
    if (j == 0) {
        float o0 = L2b[0], o1 = L2b[1];
        for (int k = 0; k < 128; ++k) {
            o0 += hid[k] * L2W[2 * k + 0];
            o1 += hid[k] * L2W[2 * k + 1];
        }
        float m = fmaxf(o0, o1);
        float lse = m + logf(expf(o0 - m) + expf(o1 - m));
        out[g * 2 + 0] = o0 - lse;
        out[g * 2 + 1] = o1 - lse;
    }
}

extern "C" void kernel_launch(void* const* d_in, const int* in_sizes, int n_in,
                              void* d_out, int out_size, void* d_ws, size_t ws_size,
                              hipStream_t stream) {
    const float* x    = (const float*)d_in[0];
    const int*   ei   = (const int*)d_in[1];    // [2, N_EDGES]: src row then dst row
    const int*   batch= (const int*)d_in[2];
    const float* W1   = (const float*)d_in[3];
    const float* b1   = (const float*)d_in[4];
    const float* W2   = (const float*)d_in[5];
    const float* b2   = (const float*)d_in[6];
    const float* L1W  = (const float*)d_in[7];
    const float* L1b  = (const float*)d_in[8];
    const float* L2W  = (const float*)d_in[9];
    const float* L2b  = (const float*)d_in[10];
    float* out = (float*)d_out;

    const int* e_src = ei;
    const int* e_dst = ei + N_EDGES;

    char* ws = (char*)d_ws;
    size_t off = 0;
    auto alloc = [&](size_t bytes) {
        void* p = ws + off;
        off += (bytes + 255) & ~(size_t)255;
        return p;
    };
    int*   cntA      = (int*)alloc((size_t)N_SEG * 4);
    int*   bsumA     = (int*)alloc(SCANA_NB * 4);
    int*   baseA     = (int*)alloc((size_t)N_SEG * 4);
    int2*  ebuf      = (int2*)alloc((size_t)N_EDGES * 8);
    int2*  sedge     = (int2*)alloc((size_t)N_EDGES * 8);
    int*   rowptr    = (int*)alloc((N_NODES + 1) * 4);
    float* dinv      = (float*)alloc(N_NODES * 4);
    float* p1        = (float*)alloc(N_GRAPHS * DIM * 4);
    float* p2        = (float*)alloc(N_GRAPHS * DIM * 4);
    unsigned short* bufBf = (unsigned short*)alloc((size_t)N_NODES * DIM * 2);
    float* bufB      = (float*)alloc((size_t)N_NODES * DIM * 4);
    (void)ws_size; (void)in_sizes; (void)n_in; (void)out_size;

    // ---- CSR build: two-level counting sort (all full-line writes) ----
    a1_count_kernel<<<A_BLOCKS, 256, 0, stream>>>(e_dst, cntA);
    reduceN_kernel<<<SCANA_NB, SCANA_B, 0, stream>>>(cntA, bsumA);
    scanblkN_kernel<<<1, 64, 0, stream>>>(bsumA);
    scanoutN_kernel<<<SCANA_NB, SCANA_B, 0, stream>>>(cntA, bsumA, baseA);
    a2_scatter_kernel<<<A_BLOCKS, 256, 0, stream>>>(e_src, e_dst, baseA, ebuf);
    bucket_kernel<<<NBUCK, 512, 0, stream>>>(ebuf, baseA, sedge, rowptr, dinv);
    weight_kernel<<<(N_EDGES + 511) / 512, 512, 0, stream>>>(sedge, dinv);

    const int MMB = (N_NODES + 127) / 128;      // 391
    const int AGB = (N_NODES * 64 + 255) / 256; // 12500

    // conv1
    mm_mfma_kernel<<<MMB, 256, 0, stream>>>(x, W1, bufBf, N_NODES);
    agg_kernel<<<AGB, 256, 0, stream>>>(bufBf, rowptr, sedge, dinv, b1, bufB);  // h1 (fp32)
    pool_kernel<<<N_GRAPHS, 512, 0, stream>>>(bufB, batch, p1);

    // conv2
    mm_mfma_kernel<<<MMB, 256, 0, stream>>>(bufB, W2, bufBf, N_NODES);
    agg_kernel<<<AGB, 256, 0, stream>>>(bufBf, rowptr, sedge, dinv, b2, bufB);  // h2
    pool_kernel<<<N_GRAPHS, 512, 0, stream>>>(bufB, batch, p2);

    // head
    mlp_kernel<<<N_GRAPHS, 128, 0, stream>>>(p1, p2, L1W, L1b, L2W, L2b, out);
}

// Round 13
// 252.645 us; speedup vs baseline: 3.0769x; 1.0885x over previous
//
#include <hip/hip_runtime.h>

#define N_NODES 50000
#define N_EDGES 800000
#define N_GRAPHS 256
#define DIM 128

// ---- two-level counting sort geometry ----
#define NBUCK 196          // ceil(50000/256), bucket = dst >> 8
#define A_BLOCKS 200
#define A_EPB 4000         // 200 * 4000 = 800000 edges exactly
#define N_SEG (NBUCK * A_BLOCKS)   // 39200 (bucket-major)
#define SCANA_B 1024
#define SCANA_NB 39        // ceil(39200/1024)

typedef __attribute__((ext_vector_type(8))) short bf16x8;
typedef __attribute__((ext_vector_type(4))) float f32x4;
typedef __attribute__((ext_vector_type(8))) unsigned short u16x8;

__device__ __forceinline__ unsigned short f2bf(float f) {
    union { float f; unsigned u; } v; v.f = f;
    unsigned u = v.u;
    u += 0x7fffu + ((u >> 16) & 1u);   // round-to-nearest-even
    return (unsigned short)(u >> 16);
}
__device__ __forceinline__ float bf2f(unsigned short h) {
    union { unsigned u; float f; } v; v.u = ((unsigned)h) << 16;
    return v.f;
}

// ---------------- A1: per-(bucket, ablock) counts ----------------
__global__ __launch_bounds__(256) void a1_count_kernel(const int* __restrict__ dst,
                                                       int* __restrict__ cntA) {
    __shared__ int hist[NBUCK];
    int t = threadIdx.x;
    for (int b = t; b < NBUCK; b += 256) hist[b] = 0;
    __syncthreads();
    int base = blockIdx.x * A_EPB;
    for (int i = t; i < A_EPB; i += 256) {
        int d = dst[base + i];
        atomicAdd(&hist[d >> 8], 1);
    }
    __syncthreads();
    for (int b = t; b < NBUCK; b += 256) cntA[b * A_BLOCKS + blockIdx.x] = hist[b];
}

// ---------------- per-block totals for the segment scan ----------------
__global__ __launch_bounds__(SCANA_B) void reduceN_kernel(const int* __restrict__ in,
                                                          int* __restrict__ bsum) {
    __shared__ int red[SCANA_B / 64];
    int idx = blockIdx.x * SCANA_B + threadIdx.x;
    int v = (idx < N_SEG) ? in[idx] : 0;
    for (int d = 32; d >= 1; d >>= 1) v += __shfl_down(v, d, 64);
    if ((threadIdx.x & 63) == 0) red[threadIdx.x >> 6] = v;
    __syncthreads();
    if (threadIdx.x == 0) {
        int s = 0;
        for (int w = 0; w < SCANA_B / 64; ++w) s += red[w];
        bsum[blockIdx.x] = s;
    }
}

// ---------------- block-local scan + self-computed block offset ----------------
__global__ __launch_bounds__(SCANA_B) void scanoutN_kernel(const int* __restrict__ in,
                                                           const int* __restrict__ bsum,
                                                           int* __restrict__ outx) {
    __shared__ int s[SCANA_B];
    __shared__ int boffs;
    int t = threadIdx.x;
    // wave 0 computes prefix of bsum[0..blockIdx.x) (SCANA_NB=39 < 64)
    if (t < 64) {
        int v = (t < blockIdx.x) ? bsum[t] : 0;
        for (int d = 32; d >= 1; d >>= 1) v += __shfl_down(v, d, 64);
        if (t == 0) boffs = v;
    }
    int idx = blockIdx.x * SCANA_B + t;
    int c = (idx < N_SEG) ? in[idx] : 0;
    s[t] = c;
    __syncthreads();
    for (int d = 1; d < SCANA_B; d <<= 1) {
        int v = s[t];
        if (t >= d) v += s[t - d];
        __syncthreads();
        s[t] = v;
        __syncthreads();
    }
    if (idx < N_SEG) outx[idx] = boffs + s[t] - c;   // exclusive
}

// ---------------- A2: scatter into bucket-segmented {src,dst} ----------------
__global__ __launch_bounds__(256) void a2_scatter_kernel(const int* __restrict__ src,
                                                         const int* __restrict__ dst,
                                                         const int* __restrict__ baseA,
                                                         int2* __restrict__ ebuf) {
    __shared__ int cur[NBUCK];
    int t = threadIdx.x;
    for (int b = t; b < NBUCK; b += 256) cur[b] = baseA[b * A_BLOCKS + blockIdx.x];
    __syncthreads();
    int base = blockIdx.x * A_EPB;
    for (int i = t; i < A_EPB; i += 256) {
        int e = base + i;
        int sN = src[e], d = dst[e];
        int pos = atomicAdd(&cur[d >> 8], 1);
        int2 r; r.x = sN; r.y = d;
        ebuf[pos] = r;
    }
}

// ---------------- B: per-bucket counting sort -> CSR + rowptr + dinv ----------------
__global__ __launch_bounds__(512) void bucket_kernel(const int2* __restrict__ ebuf,
                                                     const int* __restrict__ baseA,
                                                     int2* __restrict__ sedge,
                                                     int* __restrict__ rowptr,
                                                     float* __restrict__ dinv) {
    int b = blockIdx.x;
    int t = threadIdx.x;
    __shared__ int cnt[256], sc[256], cur[256];
    __shared__ int se[2];
    if (t == 0) {
        se[0] = baseA[b * A_BLOCKS];
        se[1] = (b + 1 < NBUCK) ? baseA[(b + 1) * A_BLOCKS] : N_EDGES;
    }
    if (t < 256) cnt[t] = 0;
    __syncthreads();
    int start = se[0], end = se[1];
    for (int i = start + t; i < end; i += 512) atomicAdd(&cnt[ebuf[i].y & 255], 1);
    __syncthreads();
    if (t < 256) sc[t] = cnt[t];
    __syncthreads();
    for (int d = 1; d < 256; d <<= 1) {
        int v = 0;
        if (t < 256) { v = sc[t]; if (t >= d) v += sc[t - d]; }
        __syncthreads();
        if (t < 256) sc[t] = v;
        __syncthreads();
    }
    if (t < 256) {
        int excl = start + sc[t] - cnt[t];
        cur[t] = excl;
        int v = b * 256 + t;
        if (v < N_NODES) {
            rowptr[v] = excl;
            dinv[v] = rsqrtf((float)(cnt[t] + 1));
        }
    }
    if (b == 0 && t == 0) rowptr[N_NODES] = N_EDGES;
    __syncthreads();
    for (int i = start + t; i < end; i += 512) {
        int2 r = ebuf[i];
        int pos = atomicAdd(&cur[r.y & 255], 1);
        sedge[pos] = r;   // {src, dst}; weights filled by weight_kernel
    }
}

// ---------------- C: in-place {src,dst} -> {src, w} ----------------
__global__ __launch_bounds__(512) void weight_kernel(int2* __restrict__ sedge,
                                                     const float* __restrict__ dinv) {
    int i = blockIdx.x * 512 + threadIdx.x;
    if (i < N_EDGES) {
        int2 r = sedge[i];
        float w = dinv[r.x] * dinv[r.y];
        r.y = __float_as_int(w);
        sedge[i] = r;
    }
}

// ---------------- MFMA matmul core (shared by f32/bf16 input variants) ----------------
#define LDK 136   // padded LDS row stride in shorts (272B = 17*16, 16B-aligned)
__device__ __forceinline__ void mm_core(const unsigned short* Xs, const unsigned short* Wt,
                                        unsigned short* __restrict__ Y, int r0, int nrows, int t) {
    int w  = t >> 6;
    int l  = t & 63;
    int lg = l >> 4;
    int lr = l & 15;

    f32x4 acc[2][8];
#pragma unroll
    for (int rs = 0; rs < 2; ++rs)
#pragma unroll
        for (int cs = 0; cs < 8; ++cs) acc[rs][cs] = (f32x4){0.f, 0.f, 0.f, 0.f};

#pragma unroll
    for (int ks = 0; ks < 4; ++ks) {
        int koff = ks * 32 + lg * 8;
        bf16x8 a0 = *(const bf16x8*)&Xs[(w * 32 + 0 + lr) * LDK + koff];
        bf16x8 a1 = *(const bf16x8*)&Xs[(w * 32 + 16 + lr) * LDK + koff];
#pragma unroll
        for (int cs = 0; cs < 8; ++cs) {
            bf16x8 b = *(const bf16x8*)&Wt[(cs * 16 + lr) * LDK + koff];
            acc[0][cs] = __builtin_amdgcn_mfma_f32_16x16x32_bf16(a0, b, acc[0][cs], 0, 0, 0);
            acc[1][cs] = __builtin_amdgcn_mfma_f32_16x16x32_bf16(a1, b, acc[1][cs], 0, 0, 0);
        }
    }

#pragma unroll
    for (int rs = 0; rs < 2; ++rs) {
        int rbase = r0 + w * 32 + rs * 16 + lg * 4;
#pragma unroll
        for (int cs = 0; cs < 8; ++cs) {
            int c = cs * 16 + lr;
#pragma unroll
            for (int reg = 0; reg < 4; ++reg) {
                int r = rbase + reg;
                if (r < nrows) Y[(size_t)r * 128 + c] = f2bf(acc[rs][cs][reg]);
            }
        }
    }
}

// conv1: fp32 input, converts while staging
__global__ __launch_bounds__(256) void mm_mfma_f32_kernel(const float* __restrict__ X,
                                                          const float* __restrict__ W,
                                                          unsigned short* __restrict__ Y,
                                                          int nrows) {
    __shared__ __align__(16) unsigned short Xs[128 * LDK];
    __shared__ __align__(16) unsigned short Wt[128 * LDK];
    int t = threadIdx.x;
    for (int idx = t; idx < 128 * 128; idx += 256) {
        int k = idx >> 7, c = idx & 127;
        Wt[c * LDK + k] = f2bf(W[idx]);
    }
    int r0 = blockIdx.x * 128;
    const float4* X4 = (const float4*)X;
    for (int idx = t; idx < 128 * 32; idx += 256) {
        int r = idx >> 5, q = idx & 31;
        int gr = r0 + r;
        float4 vv = (gr < nrows) ? X4[(size_t)gr * 32 + q] : make_float4(0.f, 0.f, 0.f, 0.f);
        int base = r * LDK + q * 4;
        Xs[base + 0] = f2bf(vv.x);
        Xs[base + 1] = f2bf(vv.y);
        Xs[base + 2] = f2bf(vv.z);
        Xs[base + 3] = f2bf(vv.w);
    }
    __syncthreads();
    mm_core(Xs, Wt, Y, r0, nrows, t);
}

// conv2: bf16 input, straight copy staging
__global__ __launch_bounds__(256) void mm_mfma_bf16_kernel(const unsigned short* __restrict__ X,
                                                           const float* __restrict__ W,
                                                           unsigned short* __restrict__ Y,
                                                           int nrows) {
    __shared__ __align__(16) unsigned short Xs[128 * LDK];
    __shared__ __align__(16) unsigned short Wt[128 * LDK];
    int t = threadIdx.x;
    for (int idx = t; idx < 128 * 128; idx += 256) {
        int k = idx >> 7, c = idx & 127;
        Wt[c * LDK + k] = f2bf(W[idx]);
    }
    int r0 = blockIdx.x * 128;
    const u16x8* X8 = (const u16x8*)X;
    u16x8 z = {0, 0, 0, 0, 0, 0, 0, 0};
    for (int idx = t; idx < 128 * 16; idx += 256) {
        int r = idx >> 4, q = idx & 15;
        int gr = r0 + r;
        u16x8 vv = (gr < nrows) ? X8[(size_t)gr * 16 + q] : z;
        *(u16x8*)&Xs[r * LDK + q * 8] = vv;
    }
    __syncthreads();
    mm_core(Xs, Wt, Y, r0, nrows, t);
}

// ---------------- aggregation: one wave per node, quarter-wave bf16 rows ----------------
// Output now bf16 (h is re-quantized to bf16 by mm staging anyway).
__global__ __launch_bounds__(256) void agg_kernel(const unsigned short* __restrict__ Hbf,
                                                  const int* __restrict__ rowptr,
                                                  const int2* __restrict__ sedge,
                                                  const float* __restrict__ dinv,
                                                  const float* __restrict__ bias,
                                                  unsigned short* __restrict__ O) {
    int gw = (int)((blockIdx.x * 256 + threadIdx.x) >> 6);
    if (gw >= N_NODES) return;
    int v = __builtin_amdgcn_readfirstlane(gw);
    int lane = threadIdx.x & 63;
    int q = lane >> 4;          // quarter: which edge in a group of 4
    int f = lane & 15;          // 16-B chunk within the 256-B row
    const u16x8* H8 = (const u16x8*)Hbf;   // row stride 16
    float a0 = 0.f, a1 = 0.f, a2 = 0.f, a3 = 0.f,
          a4 = 0.f, a5 = 0.f, a6 = 0.f, a7 = 0.f;
    int e0 = rowptr[v], eend = rowptr[v + 1];
    for (int base = e0; base < eend; base += 16) {
#pragma unroll
        for (int k = 0; k < 4; ++k) {
            int ee = base + 4 * k + q;
            bool inb = ee < eend;
            int ec = inb ? ee : e0;
            int2 rec = sedge[ec];
            int s = rec.x;
            float w = inb ? __int_as_float(rec.y) : 0.f;
            u16x8 h = H8[(size_t)s * 16 + f];
            a0 += w * bf2f(h[0]);
            a1 += w * bf2f(h[1]);
            a2 += w * bf2f(h[2]);
            a3 += w * bf2f(h[3]);
            a4 += w * bf2f(h[4]);
            a5 += w * bf2f(h[5]);
            a6 += w * bf2f(h[6]);
            a7 += w * bf2f(h[7]);
        }
    }
    a0 += __shfl_xor(a0, 16, 64); a0 += __shfl_xor(a0, 32, 64);
    a1 += __shfl_xor(a1, 16, 64); a1 += __shfl_xor(a1, 32, 64);
    a2 += __shfl_xor(a2, 16, 64); a2 += __shfl_xor(a2, 32, 64);
    a3 += __shfl_xor(a3, 16, 64); a3 += __shfl_xor(a3, 32, 64);
    a4 += __shfl_xor(a4, 16, 64); a4 += __shfl_xor(a4, 32, 64);
    a5 += __shfl_xor(a5, 16, 64); a5 += __shfl_xor(a5, 32, 64);
    a6 += __shfl_xor(a6, 16, 64); a6 += __shfl_xor(a6, 32, 64);
    a7 += __shfl_xor(a7, 16, 64); a7 += __shfl_xor(a7, 32, 64);
    if (q == 0) {
        float dv = dinv[v];
        float sc = dv * dv;
        u16x8 hs = H8[(size_t)v * 16 + f];
        float4 b4a = ((const float4*)bias)[f * 2 + 0];
        float4 b4b = ((const float4*)bias)[f * 2 + 1];
        u16x8 o;
        o[0] = f2bf(fmaxf(a0 + sc * bf2f(hs[0]) + b4a.x, 0.f));
        o[1] = f2bf(fmaxf(a1 + sc * bf2f(hs[1]) + b4a.y, 0.f));
        o[2] = f2bf(fmaxf(a2 + sc * bf2f(hs[2]) + b4a.z, 0.f));
        o[3] = f2bf(fmaxf(a3 + sc * bf2f(hs[3]) + b4a.w, 0.f));
        o[4] = f2bf(fmaxf(a4 + sc * bf2f(hs[4]) + b4b.x, 0.f));
        o[5] = f2bf(fmaxf(a5 + sc * bf2f(hs[5]) + b4b.y, 0.f));
        o[6] = f2bf(fmaxf(a6 + sc * bf2f(hs[6]) + b4b.z, 0.f));
        o[7] = f2bf(fmaxf(a7 + sc * bf2f(hs[7]) + b4b.w, 0.f));
        ((u16x8*)O)[(size_t)v * 16 + f] = o;
    }
}

// ---------------- mean pool per graph (batch is sorted), bf16 input ----------------
__device__ __forceinline__ int lbound(const int* __restrict__ a, int n, int v) {
    int lo = 0, hi = n;
    while (lo < hi) {
        int mid = (lo + hi) >> 1;
        if (a[mid] < v) lo = mid + 1; else hi = mid;
    }
    return lo;
}

__global__ __launch_bounds__(512) void pool_kernel(const unsigned short* __restrict__ H,
                                                   const int* __restrict__ batch,
                                                   float* __restrict__ P) {
    int g = blockIdx.x;
    __shared__ int sse[2];
    __shared__ float red[32][129];   // padded: column reads conflict-free
    int t = threadIdx.x;
    if (t < 2) sse[t] = lbound(batch, N_NODES, g + t);
    __syncthreads();
    int ss = sse[0], se = sse[1];
    int f = t & 15, c = t >> 4;      // 16 chunks x 32 node-lanes
    const u16x8* H8 = (const u16x8*)H;
    float a[8] = {0.f, 0.f, 0.f, 0.f, 0.f, 0.f, 0.f, 0.f};
    for (int n = ss + c; n < se; n += 32) {
        u16x8 h = H8[(size_t)n * 16 + f];
#pragma unroll
        for (int k = 0; k < 8; ++k) a[k] += bf2f(h[k]);
    }
#pragma unroll
    for (int k = 0; k < 8; ++k) red[c][f * 8 + k] = a[k];
    __syncthreads();
    if (t < 128) {
        float s = 0.f;
#pragma unroll 8
        for (int c2 = 0; c2 < 32; ++c2) s += red[c2][t];
        float cntf = (float)(se - ss);
        P[g * 128 + t] = s / fmaxf(cntf, 1.f);
    }
}

// ---------------- MLP + log_softmax ----------------
__global__ __launch_bounds__(128) void mlp_kernel(const float* __restrict__ P1,
                                                  const float* __restrict__ P2,
                                                  const float* __restrict__ L1W,
                                                  const float* __restrict__ L1b,
                                                  const float* __restrict__ L2W,
                                                  const float* __restrict__ L2b,
                                                  float* __restrict__ out) {
    int g = blockIdx.x, j = threadIdx.x;
    __shared__ float gv[256];
    __shared__ float hid[128];
    gv[j] = P1[g * 128 + j];
    gv[128 + j] = P2[g * 128 + j];
    __syncthreads();
    float acc = L1b[j];
#pragma unroll 8
    for (int k = 0; k < 256; ++k) acc = fmaf(gv[k], L1W[k * 128 + j], acc);
    hid[j] = fmaxf(acc, 0.f);
    __syncthreads();
    if (j == 0) {
        float o0 = L2b[0], o1 = L2b[1];
        for (int k = 0; k < 128; ++k) {
            o0 += hid[k] * L2W[2 * k + 0];
            o1 += hid[k] * L2W[2 * k + 1];
        }
        float m = fmaxf(o0, o1);
        float lse = m + logf(expf(o0 - m) + expf(o1 - m));
        out[g * 2 + 0] = o0 - lse;
        out[g * 2 + 1] = o1 - lse;
    }
}

extern "C" void kernel_launch(void* const* d_in, const int* in_sizes, int n_in,
                              void* d_out, int out_size, void* d_ws, size_t ws_size,
                              hipStream_t stream) {
    const float* x    = (const float*)d_in[0];
    const int*   ei   = (const int*)d_in[1];    // [2, N_EDGES]: src row then dst row
    const int*   batch= (const int*)d_in[2];
    const float* W1   = (const float*)d_in[3];
    const float* b1   = (const float*)d_in[4];
    const float* W2   = (const float*)d_in[5];
    const float* b2   = (const float*)d_in[6];
    const float* L1W  = (const float*)d_in[7];
    const float* L1b  = (const float*)d_in[8];
    const float* L2W  = (const float*)d_in[9];
    const float* L2b  = (const float*)d_in[10];
    float* out = (float*)d_out;

    const int* e_src = ei;
    const int* e_dst = ei + N_EDGES;

    char* ws = (char*)d_ws;
    size_t off = 0;
    auto alloc = [&](size_t bytes) {
        void* p = ws + off;
        off += (bytes + 255) & ~(size_t)255;
        return p;
    };
    int*   cntA      = (int*)alloc((size_t)N_SEG * 4);
    int*   bsumA     = (int*)alloc(SCANA_NB * 4);
    int*   baseA     = (int*)alloc((size_t)N_SEG * 4);
    int2*  ebuf      = (int2*)alloc((size_t)N_EDGES * 8);
    int2*  sedge     = (int2*)alloc((size_t)N_EDGES * 8);
    int*   rowptr    = (int*)alloc((N_NODES + 1) * 4);
    float* dinv      = (float*)alloc(N_NODES * 4);
    float* p1        = (float*)alloc(N_GRAPHS * DIM * 4);
    float* p2        = (float*)alloc(N_GRAPHS * DIM * 4);
    unsigned short* bufBf = (unsigned short*)alloc((size_t)N_NODES * DIM * 2);
    unsigned short* bufH  = (unsigned short*)alloc((size_t)N_NODES * DIM * 2);
    (void)ws_size; (void)in_sizes; (void)n_in; (void)out_size;

    // ---- CSR build: two-level counting sort (all full-line writes) ----
    a1_count_kernel<<<A_BLOCKS, 256, 0, stream>>>(e_dst, cntA);
    reduceN_kernel<<<SCANA_NB, SCANA_B, 0, stream>>>(cntA, bsumA);
    scanoutN_kernel<<<SCANA_NB, SCANA_B, 0, stream>>>(cntA, bsumA, baseA);
    a2_scatter_kernel<<<A_BLOCKS, 256, 0, stream>>>(e_src, e_dst, baseA, ebuf);
    bucket_kernel<<<NBUCK, 512, 0, stream>>>(ebuf, baseA, sedge, rowptr, dinv);
    weight_kernel<<<(N_EDGES + 511) / 512, 512, 0, stream>>>(sedge, dinv);

    const int MMB = (N_NODES + 127) / 128;      // 391
    const int AGB = (N_NODES * 64 + 255) / 256; // 12500

    // conv1
    mm_mfma_f32_kernel<<<MMB, 256, 0, stream>>>(x, W1, bufBf, N_NODES);
    agg_kernel<<<AGB, 256, 0, stream>>>(bufBf, rowptr, sedge, dinv, b1, bufH);  // h1 (bf16)
    pool_kernel<<<N_GRAPHS, 512, 0, stream>>>(bufH, batch, p1);

    // conv2
    mm_mfma_bf16_kernel<<<MMB, 256, 0, stream>>>(bufH, W2, bufBf, N_NODES);
    agg_kernel<<<AGB, 256, 0, stream>>>(bufBf, rowptr, sedge, dinv, b2, bufH);  // h2 (bf16)
    pool_kernel<<<N_GRAPHS, 512, 0, stream>>>(bufH, batch, p2);

    // head
    mlp_kernel<<<N_GRAPHS, 128, 0, stream>>>(p1, p2, L1W, L1b, L2W, L2b, out);
}